// Round 14
// baseline (156.426 us; speedup 1.0000x reference)
//
#include <hip/hip_runtime.h>
#include <hip/hip_bf16.h>
#include <stdint.h>

typedef __attribute__((ext_vector_type(8))) _Float16 f16x8;
typedef __attribute__((ext_vector_type(4))) _Float16 f16x4;
typedef __attribute__((ext_vector_type(4))) float f32x4;

static constexpr int BATCH = 2;
static constexpr int SEQ = 2048;
static constexpr int EMB = 1024;
static constexpr int NH = 16;
static constexpr int HD_ = 64;

#define AS1 __attribute__((address_space(1)))
#define AS3 __attribute__((address_space(3)))

__device__ __forceinline__ void gload_lds16(const void* g, void* l) {
  __builtin_amdgcn_global_load_lds((const AS1 uint32_t*)g, (AS3 uint32_t*)l, 16, 0, 0);
}

__device__ __forceinline__ f32x4 mfma16(f16x8 a, f16x8 b, f32x4 c) {
  return __builtin_amdgcn_mfma_f32_16x16x32_f16(a, b, c, 0, 0, 0);
}

// swizzled 16B-block read from a 128B-row LDS tile: byte ^= (row&7)<<4
__device__ __forceinline__ f16x8 swzread(const _Float16* base, int row, int blk) {
  return *(const f16x8*)((const char*)base + row * 128 +
                         ((blk * 16) ^ ((row & 7) << 4)));
}

// ---------------- convert f32 -> f16 ----------------
__global__ __launch_bounds__(256) void k_convert(const float* __restrict__ in,
                                                 _Float16* __restrict__ oh, int n4) {
  int idx = blockIdx.x * 256 + threadIdx.x;
  if (idx >= n4) return;
  float4 v = reinterpret_cast<const float4*>(in)[idx];
  const float* f = reinterpret_cast<const float*>(&v);
  _Float16 h[4];
#pragma unroll
  for (int i = 0; i < 4; ++i) h[i] = (_Float16)f[i];
  reinterpret_cast<uint2*>(oh)[idx] = *reinterpret_cast<uint2*>(h);
}

// ---------------- transpose+convert to f16: in[R][C] f32 -> out[perm(C)][R] ----------------
// PERM 1: Wqkv column permutation to [q(1024) | k(1024) | v(1024)]
template <int PERM>
__global__ __launch_bounds__(256) void k_transpose(const float* __restrict__ in,
                                                   _Float16* __restrict__ out, int R,
                                                   int C) {
  __shared__ float tile[32][33];
  const int t = threadIdx.x;
  const int tr = t >> 5, tc = t & 31;
  const int r0 = blockIdx.y * 32, c0 = blockIdx.x * 32;
#pragma unroll
  for (int rr = 0; rr < 32; rr += 8)
    tile[tr + rr][tc] = in[(size_t)(r0 + tr + rr) * C + c0 + tc];
  __syncthreads();
#pragma unroll
  for (int rr = 0; rr < 32; rr += 8) {
    const int c = c0 + tr + rr;
    int d = c;
    if constexpr (PERM) {
      const int h = c / 192, r = c - h * 192;
      d = (r < 64) ? h * 64 + r
                   : (r < 128 ? 1024 + h * 64 + (r - 64) : 2048 + h * 64 + (r - 128));
    }
    out[(size_t)d * R + r0 + tc] = (_Float16)tile[tc][tr + rr];
  }
}

// ---------------- QKV GEMM: A f16[4096][1024] x Bt f16[3072][1024]^T, 1 MFMA ---------
// epilogue scatter: q_s f16 (x 8*log2e), k_s f16, v_t f16 transposed (f16x4 stores)
__global__ __launch_bounds__(256) void k_gemm_qkv(const _Float16* __restrict__ A,
                                                  const _Float16* __restrict__ Bt,
                                                  const float* __restrict__ bias,
                                                  _Float16* __restrict__ oq,
                                                  _Float16* __restrict__ ok,
                                                  _Float16* __restrict__ ov) {
  constexpr int K = EMB;
  __shared__ _Float16 As[2][128 * 32];
  __shared__ _Float16 Bs[2][128 * 32];
  const int t = threadIdx.x;
  const int l = t & 63, w = t >> 6;
  const int lr = l & 15, lg = l >> 4;
  const int wr = w >> 1, wc = w & 1;
  const int m0 = blockIdx.y * 128, n0 = blockIdx.x * 128;

  auto stage = [&](int buf, int k0) {
#pragma unroll
    for (int j = 0; j < 2; ++j) {
      const int c = t + 256 * j;
      const int row = c >> 2, cb = c & 3;
      gload_lds16(A + (size_t)(m0 + row) * K + k0 + cb * 8, &As[buf][c * 8]);
      gload_lds16(Bt + (size_t)(n0 + row) * K + k0 + cb * 8, &Bs[buf][c * 8]);
    }
  };

  f32x4 acc[4][4];
#pragma unroll
  for (int m = 0; m < 4; ++m)
#pragma unroll
    for (int n = 0; n < 4; ++n) acc[m][n] = f32x4{0.f, 0.f, 0.f, 0.f};

  stage(0, 0);
  const int NT = K / 32;
  int cur = 0;
  for (int kt = 0; kt < NT; ++kt) {
    __syncthreads();
    if (kt + 1 < NT) stage(cur ^ 1, (kt + 1) * 32);
    f16x8 af[4], bf[4];
#pragma unroll
    for (int m = 0; m < 4; ++m)
      af[m] = *(const f16x8*)&As[cur][(wr * 64 + m * 16 + lr) * 32 + lg * 8];
#pragma unroll
    for (int n = 0; n < 4; ++n)
      bf[n] = *(const f16x8*)&Bs[cur][(wc * 64 + n * 16 + lr) * 32 + lg * 8];
#pragma unroll
    for (int m = 0; m < 4; ++m)
#pragma unroll
      for (int n = 0; n < 4; ++n) acc[m][n] = mfma16(af[m], bf[n], acc[m][n]);
    cur ^= 1;
  }

  const int sec = n0 >> 10;  // 0=q 1=k 2=v (block-uniform)
#pragma unroll
  for (int m = 0; m < 4; ++m) {
#pragma unroll
    for (int n = 0; n < 4; ++n) {
      const int col = n0 + wc * 64 + n * 16 + lr;
      const int cc = col & 1023;
      const int h = cc >> 6, r = cc & 63;
      const float bv = bias[h * 192 + sec * 64 + r];
      const int row0 = m0 + wr * 64 + m * 16 + lg * 4;
      const int b = row0 >> 11, s0 = row0 & (SEQ - 1);
      if (sec == 2) {  // V^T: i -> s consecutive, 4-aligned -> one 8B store
        f16x4 vv;
#pragma unroll
        for (int i = 0; i < 4; ++i) vv[i] = (_Float16)(acc[m][n][i] + bv);
        *(f16x4*)&ov[(((size_t)b * NH + h) * HD_ + r) * SEQ + s0] = vv;
      } else {
#pragma unroll
        for (int i = 0; i < 4; ++i) {
          const float v = acc[m][n][i] + bv;
          const size_t dst = (((size_t)b * NH + h) * SEQ + s0 + i) * HD_ + r;
          if (sec == 0)
            oq[dst] = (_Float16)(v * 11.5415603f);  // 8*log2(e) folded
          else
            ok[dst] = (_Float16)v;
        }
      }
    }
  }
}

// ---------------- proj GEMM: a_o f16 x Wproj_t f16^T -> f32 + bias ----------------
__global__ __launch_bounds__(256) void k_gemm_proj(const _Float16* __restrict__ A,
                                                   const _Float16* __restrict__ Bt,
                                                   const float* __restrict__ bias,
                                                   float* __restrict__ of) {
  constexpr int K = EMB, N = EMB;
  __shared__ _Float16 As[2][128 * 32];
  __shared__ _Float16 Bs[2][128 * 32];
  const int t = threadIdx.x;
  const int l = t & 63, w = t >> 6;
  const int lr = l & 15, lg = l >> 4;
  const int wr = w >> 1, wc = w & 1;
  const int m0 = blockIdx.y * 128, n0 = blockIdx.x * 128;

  auto stage = [&](int buf, int k0) {
#pragma unroll
    for (int j = 0; j < 2; ++j) {
      const int c = t + 256 * j;
      const int row = c >> 2, cb = c & 3;
      gload_lds16(A + (size_t)(m0 + row) * K + k0 + cb * 8, &As[buf][c * 8]);
      gload_lds16(Bt + (size_t)(n0 + row) * K + k0 + cb * 8, &Bs[buf][c * 8]);
    }
  };

  f32x4 acc[4][4];
#pragma unroll
  for (int m = 0; m < 4; ++m)
#pragma unroll
    for (int n = 0; n < 4; ++n) acc[m][n] = f32x4{0.f, 0.f, 0.f, 0.f};

  stage(0, 0);
  const int NT = K / 32;
  int cur = 0;
  for (int kt = 0; kt < NT; ++kt) {
    __syncthreads();
    if (kt + 1 < NT) stage(cur ^ 1, (kt + 1) * 32);
    f16x8 af[4], bf[4];
#pragma unroll
    for (int m = 0; m < 4; ++m)
      af[m] = *(const f16x8*)&As[cur][(wr * 64 + m * 16 + lr) * 32 + lg * 8];
#pragma unroll
    for (int n = 0; n < 4; ++n)
      bf[n] = *(const f16x8*)&Bs[cur][(wc * 64 + n * 16 + lr) * 32 + lg * 8];
#pragma unroll
    for (int m = 0; m < 4; ++m)
#pragma unroll
      for (int n = 0; n < 4; ++n) acc[m][n] = mfma16(af[m], bf[n], acc[m][n]);
    cur ^= 1;
  }

#pragma unroll
  for (int m = 0; m < 4; ++m)
#pragma unroll
    for (int n = 0; n < 4; ++n)
#pragma unroll
      for (int i = 0; i < 4; ++i) {
        const int row = m0 + wr * 64 + m * 16 + lg * 4 + i;
        const int col = n0 + wc * 64 + n * 16 + lr;
        of[(size_t)row * N + col] = acc[m][n][i] + bias[col];
      }
}

// ---------------- flash attention, KV-split (R10 proven body + negligible-tile skip) --
// grid 1024: (bh, 128 q-rows, kv-half). Emits unnormalized partial O (f16) +
// per-row (m, lsum). 48KB LDS; T21 swizzle; defer-max THR=8 (base-2).
// Skip: if the whole tile's max is < mr-24, its contribution is < 64*2^-24
// relative (< 4e-6) -> skip softmax+P+PV entirely (staging already issued).
__global__ __launch_bounds__(512) void k_attn(
    const _Float16* __restrict__ qs, const _Float16* __restrict__ ks,
    const _Float16* __restrict__ vt, _Float16* __restrict__ op,
    float* __restrict__ marr, float* __restrict__ larr) {
  __shared__ _Float16 Kt[2][64][64];   // [buf][kv][d]   swizzled rows (128B)
  __shared__ _Float16 Vt[2][64][64];   // [buf][d][kv]   swizzled rows
  __shared__ _Float16 Pl[8][16][64];   // per-wave P [q][kv], swizzled rows
  const int t = threadIdx.x;
  const int l = t & 63, w = t >> 6;          // w in [0,8)
  const int lr = l & 15, lg = l >> 4;
  // XCD-grouping: id&7 -> XCD; per XCD: 4 heads x 16 q-blocks x 2 halves
  const int id = blockIdx.x;
  const int xc = id & 7, m_ = id >> 3;       // m_ in [0,128)
  const int kvh = m_ & 1;
  const int bh = xc + 8 * (m_ >> 5);
  const int qb = ((m_ >> 1) & 15) * 128 + w * 16;
  const int kvbase = kvh * (SEQ / 2);

  // Q fragments (B-operand: n=q=lr, k=d)
  const size_t qoff = ((size_t)bh * SEQ + qb + lr) * HD_;
  const f16x8 qf0 = *(const f16x8*)(qs + qoff + lg * 8);
  const f16x8 qf1 = *(const f16x8*)(qs + qoff + 32 + lg * 8);

  const _Float16* kbase = ks + (size_t)bh * SEQ * HD_;
  const _Float16* vbase = vt + (size_t)bh * HD_ * SEQ;

  // async staging: 512 threads cover the 64x64 tile in one pass each for K,V.
  // LDS dest linear (DMA rule); global SOURCE block pre-swizzled (T21).
  const int srow = t >> 3, scb = t & 7;      // srow in [0,64)
  auto stage = [&](const int buf, const int kv0) {
    gload_lds16(kbase + (size_t)(kv0 + srow) * HD_ + (scb ^ (srow & 7)) * 8,
                &Kt[buf][srow][scb * 8]);
    gload_lds16(vbase + (size_t)srow * SEQ + kv0 + (scb ^ (srow & 7)) * 8,
                &Vt[buf][srow][scb * 8]);
  };

  stage(0, kvbase);

  float mr = -1e30f, lsum = 0.f;
  f32x4 oacc[4];
#pragma unroll
  for (int n = 0; n < 4; ++n) oacc[n] = f32x4{0.f, 0.f, 0.f, 0.f};

  const int NT = SEQ / 128;  // 16 tiles per half
  for (int it = 0; it < NT; ++it) {
    const int cur = it & 1;
    __syncthreads();  // drains vmcnt: buf[cur] DMA complete; prev reads done
    if (it + 1 < NT) stage(cur ^ 1, kvbase + (it + 1) * 64);

    // S^T = K Q^T : lane holds S[kv=16*t4+4*lg+i][q=lr]   (base-2 logits)
    f32x4 sa[4];
    __builtin_amdgcn_s_setprio(1);
#pragma unroll
    for (int t4 = 0; t4 < 4; ++t4) {
      const int r = t4 * 16 + lr;
      const f16x8 kf0 = swzread(&Kt[cur][0][0], r, lg);
      const f16x8 kf1 = swzread(&Kt[cur][0][0], r, lg + 4);
      f32x4 s = mfma16(kf0, qf0, f32x4{0.f, 0.f, 0.f, 0.f});
      sa[t4] = mfma16(kf1, qf1, s);
    }
    __builtin_amdgcn_s_setprio(0);

    // online softmax (per-lane q-row), defer-max with THR=8 (base-2)
    float t01 = fmaxf(fmaxf(sa[0][0], sa[0][1]), fmaxf(sa[0][2], sa[0][3]));
    float t23 = fmaxf(fmaxf(sa[1][0], sa[1][1]), fmaxf(sa[1][2], sa[1][3]));
    float t45 = fmaxf(fmaxf(sa[2][0], sa[2][1]), fmaxf(sa[2][2], sa[2][3]));
    float t67 = fmaxf(fmaxf(sa[3][0], sa[3][1]), fmaxf(sa[3][2], sa[3][3]));
    float tm = fmaxf(fmaxf(t01, t23), fmaxf(t45, t67));
    tm = fmaxf(tm, __shfl_xor(tm, 16));
    tm = fmaxf(tm, __shfl_xor(tm, 32));

    // negligible-tile skip: whole tile < 2^-24 relative to running max
    if (__all(tm < mr - 24.0f)) continue;

    if (__any(tm > mr + 8.0f)) {  // wave-uniform rescale
      const float nm = fmaxf(mr, tm);
      const float corr = exp2f(mr - nm);
      mr = nm;
      lsum *= corr;
      float cb4[4];
#pragma unroll
      for (int i = 0; i < 4; ++i)
        cb4[i] = __shfl(corr, (l & 48) + ((l >> 4) << 2) + i);
#pragma unroll
      for (int n = 0; n < 4; ++n)
#pragma unroll
        for (int i = 0; i < 4; ++i) oacc[n][i] *= cb4[i];
    }

    float ts = 0.f;
    char* plbase = (char*)&Pl[w][0][0];
#pragma unroll
    for (int t4 = 0; t4 < 4; ++t4) {
      f16x4 pp;
#pragma unroll
      for (int i = 0; i < 4; ++i) {
        const float p = exp2f(sa[t4][i] - mr);
        ts += p;
        pp[i] = (_Float16)p;
      }
      // P[q=lr][kv=t4*16+lg*4+i], swizzled row (XOR bits 4-6, 8B aligned)
      *(f16x4*)(plbase + lr * 128 + ((t4 * 32 + lg * 8) ^ ((lr & 7) << 4))) = pp;
    }
    ts += __shfl_xor(ts, 16);
    ts += __shfl_xor(ts, 32);
    lsum += ts;

    // O += P V (A=P[q][kv], B=V^T[d][kv])
    const f16x8 aP0 = swzread(&Pl[w][0][0], lr, lg);
    const f16x8 aP1 = swzread(&Pl[w][0][0], lr, lg + 4);
    __builtin_amdgcn_s_setprio(1);
#pragma unroll
    for (int n = 0; n < 4; ++n) {
      const int d = n * 16 + lr;
      const f16x8 bv0 = swzread(&Vt[cur][0][0], d, lg);
      const f16x8 bv1 = swzread(&Vt[cur][0][0], d, lg + 4);
      oacc[n] = mfma16(aP0, bv0, oacc[n]);
      oacc[n] = mfma16(aP1, bv1, oacc[n]);
    }
    __builtin_amdgcn_s_setprio(0);
  }

  // epilogue: write per-row (m, lsum) — lanes 0-15 hold rows lr=l
  const size_t mlbase = ((size_t)kvh * 32 + bh) * SEQ + qb;
  if (l < 16) {
    marr[mlbase + l] = mr;
    larr[mlbase + l] = lsum;
  }
  // store unnormalized partial O as f16
  _Float16* opb = op + (size_t)kvh * BATCH * SEQ * EMB;
  const int b = bh >> 4, h = bh & 15;
#pragma unroll
  for (int n = 0; n < 4; ++n)
#pragma unroll
    for (int i = 0; i < 4; ++i) {
      const int row = qb + ((l >> 4) << 2) + i;
      opb[((size_t)b * SEQ + row) * EMB + h * HD_ + n * 16 + lr] =
          (_Float16)oacc[n][i];
    }
}

// ---------------- combine the two KV-halves ----------------
__global__ __launch_bounds__(256) void k_combine(const _Float16* __restrict__ op,
                                                 const float* __restrict__ marr,
                                                 const float* __restrict__ larr,
                                                 _Float16* __restrict__ ao) {
  const int idx = blockIdx.x * 256 + threadIdx.x;  // [0, B*S*E/8)
  const int e8 = idx & 127;                        // EMB/8 = 128
  const size_t rs = (size_t)(idx >> 7);            // b*SEQ + s
  const int h = e8 >> 3;
  const int b = (int)(rs >> 11);
  const size_t s = rs & (SEQ - 1);
  const size_t mi = ((size_t)b * NH + h) * SEQ + s;
  const float m1 = marr[mi], l1 = larr[mi];
  const float m2 = marr[(size_t)32 * SEQ + mi], l2 = larr[(size_t)32 * SEQ + mi];
  const float mx = fmaxf(m1, m2);
  const float w1 = exp2f(m1 - mx), w2 = exp2f(m2 - mx);
  const float inv = 1.0f / (l1 * w1 + l2 * w2);
  const f16x8 o1 = ((const f16x8*)op)[idx];
  const f16x8 o2 = ((const f16x8*)op)[idx + (BATCH * SEQ * EMB / 8)];
  f16x8 r;
#pragma unroll
  for (int j = 0; j < 8; ++j)
    r[j] = (_Float16)(((float)o1[j] * w1 + (float)o2[j] * w2) * inv);
  ((f16x8*)ao)[idx] = r;
}

extern "C" void kernel_launch(void* const* d_in, const int* in_sizes, int n_in,
                              void* d_out, int out_size, void* d_ws, size_t ws_size,
                              hipStream_t stream) {
  const float* query = (const float*)d_in[0];
  const float* Wqkv = (const float*)d_in[3];
  const float* bqkv = (const float*)d_in[4];
  const float* Wproj = (const float*)d_in[5];
  const float* bproj = (const float*)d_in[6];
  float* out = (float*)d_out;

  char* ws = (char*)d_ws;
  const size_t MB = 1024 * 1024;
  _Float16* q_f16   = (_Float16*)(ws + 0);         // 8MB; dead after QKV GEMM
  _Float16* Wqkv_t  = (_Float16*)(ws + 16 * MB);   // 6MB f16 (rows: q|k|v)
  _Float16* q_s     = (_Float16*)(ws + 24 * MB);   // 8MB [32][2048][64]
  _Float16* k_s     = (_Float16*)(ws + 32 * MB);   // 8MB
  _Float16* v_t     = (_Float16*)(ws + 40 * MB);   // 8MB [32][64][2048]
  _Float16* op      = (_Float16*)(ws + 0);         // 16MB partials (alias q_f16 + spare)
  _Float16* Wproj_t = (_Float16*)(ws + 48 * MB);   // 2MB
  float*    marr    = (float*)(ws + 50 * MB);      // 512KB [2][32][2048]
  float*    larr    = (float*)(ws + 50 * MB + 512 * 1024);  // 512KB
  _Float16* a_o     = (_Float16*)(ws + 51 * MB);   // 8MB

  const int M = BATCH * SEQ;  // 4096
  k_convert<<<(M * EMB / 4 + 255) / 256, 256, 0, stream>>>(query, q_f16, M * EMB / 4);
  k_transpose<1><<<dim3(3 * EMB / 32, EMB / 32), 256, 0, stream>>>(Wqkv, Wqkv_t, EMB,
                                                                   3 * EMB);
  k_gemm_qkv<<<dim3(24, M / 128), 256, 0, stream>>>(q_f16, Wqkv_t, bqkv, q_s, k_s, v_t);
  k_transpose<0><<<dim3(EMB / 32, EMB / 32), 256, 0, stream>>>(Wproj, Wproj_t, EMB, EMB);
  k_attn<<<dim3(1024), 512, 0, stream>>>(q_s, k_s, v_t, op, marr, larr);
  k_combine<<<dim3(BATCH * SEQ * EMB / 8 / 256), 256, 0, stream>>>(op, marr, larr, a_o);
  k_gemm_proj<<<dim3(EMB / 128, M / 128), 256, 0, stream>>>(a_o, Wproj_t, bproj, out);
}

// Round 15
// 154.060 us; speedup vs baseline: 1.0154x; 1.0154x over previous
//
#include <hip/hip_runtime.h>
#include <hip/hip_bf16.h>
#include <stdint.h>

typedef __attribute__((ext_vector_type(8))) _Float16 f16x8;
typedef __attribute__((ext_vector_type(4))) _Float16 f16x4;
typedef __attribute__((ext_vector_type(4))) float f32x4;

static constexpr int BATCH = 2;
static constexpr int SEQ = 2048;
static constexpr int EMB = 1024;
static constexpr int NH = 16;
static constexpr int HD_ = 64;

#define AS1 __attribute__((address_space(1)))
#define AS3 __attribute__((address_space(3)))

__device__ __forceinline__ void gload_lds16(const void* g, void* l) {
  __builtin_amdgcn_global_load_lds((const AS1 uint32_t*)g, (AS3 uint32_t*)l, 16, 0, 0);
}

__device__ __forceinline__ f32x4 mfma16(f16x8 a, f16x8 b, f32x4 c) {
  return __builtin_amdgcn_mfma_f32_16x16x32_f16(a, b, c, 0, 0, 0);
}

// swizzled 16B-block read from a 128B-row LDS tile: byte ^= (row&7)<<4
__device__ __forceinline__ f16x8 swzread(const _Float16* base, int row, int blk) {
  return *(const f16x8*)((const char*)base + row * 128 +
                         ((blk * 16) ^ ((row & 7) << 4)));
}

// ---------------- merged prep: convert q -> f16, transpose Wqkv (perm), Wproj --------
// blocks [0,4096): q convert; [4096,7168): Wqkv transpose+perm; [7168,8192): Wproj.
__global__ __launch_bounds__(256) void k_prep(const float* __restrict__ q,
                                              _Float16* __restrict__ qo,
                                              const float* __restrict__ wqkv,
                                              _Float16* __restrict__ wqkvo,
                                              const float* __restrict__ wproj,
                                              _Float16* __restrict__ wprojo) {
  __shared__ float tile[32][33];
  const int blk = blockIdx.x;
  const int t = threadIdx.x;
  if (blk < 4096) {  // convert: 4096*256 float4 = 4096*1024 floats
    const int idx = blk * 256 + t;
    float4 v = reinterpret_cast<const float4*>(q)[idx];
    const float* f = reinterpret_cast<const float*>(&v);
    _Float16 h[4];
#pragma unroll
    for (int i = 0; i < 4; ++i) h[i] = (_Float16)f[i];
    reinterpret_cast<uint2*>(qo)[idx] = *reinterpret_cast<uint2*>(h);
    return;
  }
  const float* in;
  _Float16* out;
  int R, C, bx, by;
  bool perm;
  if (blk < 4096 + 3072) {  // Wqkv: grid (96, 32)
    const int lo = blk - 4096;
    bx = lo % 96;
    by = lo / 96;
    in = wqkv; out = wqkvo; R = 1024; C = 3072; perm = true;
  } else {  // Wproj: grid (32, 32)
    const int lo = blk - 7168;
    bx = lo & 31;
    by = lo >> 5;
    in = wproj; out = wprojo; R = 1024; C = 1024; perm = false;
  }
  const int tr = t >> 5, tc = t & 31;
  const int r0 = by * 32, c0 = bx * 32;
#pragma unroll
  for (int rr = 0; rr < 32; rr += 8)
    tile[tr + rr][tc] = in[(size_t)(r0 + tr + rr) * C + c0 + tc];
  __syncthreads();
#pragma unroll
  for (int rr = 0; rr < 32; rr += 8) {
    const int c = c0 + tr + rr;
    int d = c;
    if (perm) {  // columns -> [q(1024) | k(1024) | v(1024)]
      const int h = c / 192, r = c - h * 192;
      d = (r < 64) ? h * 64 + r
                   : (r < 128 ? 1024 + h * 64 + (r - 64) : 2048 + h * 64 + (r - 128));
    }
    out[(size_t)d * R + r0 + tc] = (_Float16)tile[tc][tr + rr];
  }
}

// ---------------- QKV GEMM: A f16[4096][1024] x Bt f16[3072][1024]^T, 1 MFMA ---------
// epilogue scatter: q_s f16 (x 8*log2e), k_s f16, v_t f16 transposed (f16x4 stores)
__global__ __launch_bounds__(256) void k_gemm_qkv(const _Float16* __restrict__ A,
                                                  const _Float16* __restrict__ Bt,
                                                  const float* __restrict__ bias,
                                                  _Float16* __restrict__ oq,
                                                  _Float16* __restrict__ ok,
                                                  _Float16* __restrict__ ov) {
  constexpr int K = EMB;
  __shared__ _Float16 As[2][128 * 32];
  __shared__ _Float16 Bs[2][128 * 32];
  const int t = threadIdx.x;
  const int l = t & 63, w = t >> 6;
  const int lr = l & 15, lg = l >> 4;
  const int wr = w >> 1, wc = w & 1;
  const int m0 = blockIdx.y * 128, n0 = blockIdx.x * 128;

  auto stage = [&](int buf, int k0) {
#pragma unroll
    for (int j = 0; j < 2; ++j) {
      const int c = t + 256 * j;
      const int row = c >> 2, cb = c & 3;
      gload_lds16(A + (size_t)(m0 + row) * K + k0 + cb * 8, &As[buf][c * 8]);
      gload_lds16(Bt + (size_t)(n0 + row) * K + k0 + cb * 8, &Bs[buf][c * 8]);
    }
  };

  f32x4 acc[4][4];
#pragma unroll
  for (int m = 0; m < 4; ++m)
#pragma unroll
    for (int n = 0; n < 4; ++n) acc[m][n] = f32x4{0.f, 0.f, 0.f, 0.f};

  stage(0, 0);
  const int NT = K / 32;
  int cur = 0;
  for (int kt = 0; kt < NT; ++kt) {
    __syncthreads();
    if (kt + 1 < NT) stage(cur ^ 1, (kt + 1) * 32);
    f16x8 af[4], bf[4];
#pragma unroll
    for (int m = 0; m < 4; ++m)
      af[m] = *(const f16x8*)&As[cur][(wr * 64 + m * 16 + lr) * 32 + lg * 8];
#pragma unroll
    for (int n = 0; n < 4; ++n)
      bf[n] = *(const f16x8*)&Bs[cur][(wc * 64 + n * 16 + lr) * 32 + lg * 8];
#pragma unroll
    for (int m = 0; m < 4; ++m)
#pragma unroll
      for (int n = 0; n < 4; ++n) acc[m][n] = mfma16(af[m], bf[n], acc[m][n]);
    cur ^= 1;
  }

  const int sec = n0 >> 10;  // 0=q 1=k 2=v (block-uniform)
#pragma unroll
  for (int m = 0; m < 4; ++m) {
#pragma unroll
    for (int n = 0; n < 4; ++n) {
      const int col = n0 + wc * 64 + n * 16 + lr;
      const int cc = col & 1023;
      const int h = cc >> 6, r = cc & 63;
      const float bv = bias[h * 192 + sec * 64 + r];
      const int row0 = m0 + wr * 64 + m * 16 + lg * 4;
      const int b = row0 >> 11, s0 = row0 & (SEQ - 1);
      if (sec == 2) {  // V^T: i -> s consecutive, 4-aligned -> one 8B store
        f16x4 vv;
#pragma unroll
        for (int i = 0; i < 4; ++i) vv[i] = (_Float16)(acc[m][n][i] + bv);
        *(f16x4*)&ov[(((size_t)b * NH + h) * HD_ + r) * SEQ + s0] = vv;
      } else {
#pragma unroll
        for (int i = 0; i < 4; ++i) {
          const float v = acc[m][n][i] + bv;
          const size_t dst = (((size_t)b * NH + h) * SEQ + s0 + i) * HD_ + r;
          if (sec == 0)
            oq[dst] = (_Float16)(v * 11.5415603f);  // 8*log2(e) folded
          else
            ok[dst] = (_Float16)v;
        }
      }
    }
  }
}

// ---------------- proj GEMM: a_o f16 x Wproj_t f16^T -> f32 + bias ----------------
__global__ __launch_bounds__(256) void k_gemm_proj(const _Float16* __restrict__ A,
                                                   const _Float16* __restrict__ Bt,
                                                   const float* __restrict__ bias,
                                                   float* __restrict__ of) {
  constexpr int K = EMB, N = EMB;
  __shared__ _Float16 As[2][128 * 32];
  __shared__ _Float16 Bs[2][128 * 32];
  const int t = threadIdx.x;
  const int l = t & 63, w = t >> 6;
  const int lr = l & 15, lg = l >> 4;
  const int wr = w >> 1, wc = w & 1;
  const int m0 = blockIdx.y * 128, n0 = blockIdx.x * 128;

  auto stage = [&](int buf, int k0) {
#pragma unroll
    for (int j = 0; j < 2; ++j) {
      const int c = t + 256 * j;
      const int row = c >> 2, cb = c & 3;
      gload_lds16(A + (size_t)(m0 + row) * K + k0 + cb * 8, &As[buf][c * 8]);
      gload_lds16(Bt + (size_t)(n0 + row) * K + k0 + cb * 8, &Bs[buf][c * 8]);
    }
  };

  f32x4 acc[4][4];
#pragma unroll
  for (int m = 0; m < 4; ++m)
#pragma unroll
    for (int n = 0; n < 4; ++n) acc[m][n] = f32x4{0.f, 0.f, 0.f, 0.f};

  stage(0, 0);
  const int NT = K / 32;
  int cur = 0;
  for (int kt = 0; kt < NT; ++kt) {
    __syncthreads();
    if (kt + 1 < NT) stage(cur ^ 1, (kt + 1) * 32);
    f16x8 af[4], bf[4];
#pragma unroll
    for (int m = 0; m < 4; ++m)
      af[m] = *(const f16x8*)&As[cur][(wr * 64 + m * 16 + lr) * 32 + lg * 8];
#pragma unroll
    for (int n = 0; n < 4; ++n)
      bf[n] = *(const f16x8*)&Bs[cur][(wc * 64 + n * 16 + lr) * 32 + lg * 8];
#pragma unroll
    for (int m = 0; m < 4; ++m)
#pragma unroll
      for (int n = 0; n < 4; ++n) acc[m][n] = mfma16(af[m], bf[n], acc[m][n]);
    cur ^= 1;
  }

#pragma unroll
  for (int m = 0; m < 4; ++m)
#pragma unroll
    for (int n = 0; n < 4; ++n)
#pragma unroll
      for (int i = 0; i < 4; ++i) {
        const int row = m0 + wr * 64 + m * 16 + lg * 4 + i;
        const int col = n0 + wc * 64 + n * 16 + lr;
        of[(size_t)row * N + col] = acc[m][n][i] + bias[col];
      }
}

// ---------------- flash attention, KV-split (R10 body + halved P buffer) ------------
// grid 1024: (bh, 128 q-rows, kv-half). P time-multiplexed through an 8KB
// per-wave half-buffer (kv 0..31 then 32..63): LDS 48->40KB for occupancy.
// Same-wave LDS ops are in-order, so half-0's aP read (issued before half-1's
// P writes) safely returns pre-overwrite data. 64B-row swizzle ((lr>>1)&3)<<4
// keeps writes and reads at 2-way bank aliasing (free).
__global__ __launch_bounds__(512) void k_attn(
    const _Float16* __restrict__ qs, const _Float16* __restrict__ ks,
    const _Float16* __restrict__ vt, _Float16* __restrict__ op,
    float* __restrict__ marr, float* __restrict__ larr) {
  __shared__ _Float16 Kt[2][64][64];    // [buf][kv][d]   swizzled rows (128B)
  __shared__ _Float16 Vt[2][64][64];    // [buf][d][kv]   swizzled rows
  __shared__ _Float16 Plh[8][16][32];   // per-wave P half [q][kv'], 64B rows
  const int t = threadIdx.x;
  const int l = t & 63, w = t >> 6;          // w in [0,8)
  const int lr = l & 15, lg = l >> 4;
  // XCD-grouping: id&7 -> XCD; per XCD: 4 heads x 16 q-blocks x 2 halves
  const int id = blockIdx.x;
  const int xc = id & 7, m_ = id >> 3;       // m_ in [0,128)
  const int kvh = m_ & 1;
  const int bh = xc + 8 * (m_ >> 5);
  const int qb = ((m_ >> 1) & 15) * 128 + w * 16;
  const int kvbase = kvh * (SEQ / 2);

  // Q fragments (B-operand: n=q=lr, k=d)
  const size_t qoff = ((size_t)bh * SEQ + qb + lr) * HD_;
  const f16x8 qf0 = *(const f16x8*)(qs + qoff + lg * 8);
  const f16x8 qf1 = *(const f16x8*)(qs + qoff + 32 + lg * 8);

  const _Float16* kbase = ks + (size_t)bh * SEQ * HD_;
  const _Float16* vbase = vt + (size_t)bh * HD_ * SEQ;

  // async staging: 512 threads cover the 64x64 tile in one pass each for K,V.
  // LDS dest linear (DMA rule); global SOURCE block pre-swizzled (T21).
  const int srow = t >> 3, scb = t & 7;      // srow in [0,64)
  auto stage = [&](const int buf, const int kv0) {
    gload_lds16(kbase + (size_t)(kv0 + srow) * HD_ + (scb ^ (srow & 7)) * 8,
                &Kt[buf][srow][scb * 8]);
    gload_lds16(vbase + (size_t)srow * SEQ + kv0 + (scb ^ (srow & 7)) * 8,
                &Vt[buf][srow][scb * 8]);
  };

  stage(0, kvbase);

  float mr = -1e30f, lsum = 0.f;
  f32x4 oacc[4];
#pragma unroll
  for (int n = 0; n < 4; ++n) oacc[n] = f32x4{0.f, 0.f, 0.f, 0.f};

  char* plbase = (char*)&Plh[w][0][0];
  const int plswz = ((lr >> 1) & 3) << 4;    // 64B-row bank swizzle

  const int NT = SEQ / 128;  // 16 tiles per half
  for (int it = 0; it < NT; ++it) {
    const int cur = it & 1;
    __syncthreads();  // drains vmcnt: buf[cur] DMA complete; prev reads done
    if (it + 1 < NT) stage(cur ^ 1, kvbase + (it + 1) * 64);

    // S^T = K Q^T : lane holds S[kv=16*t4+4*lg+i][q=lr]   (base-2 logits)
    f32x4 sa[4];
    __builtin_amdgcn_s_setprio(1);
#pragma unroll
    for (int t4 = 0; t4 < 4; ++t4) {
      const int r = t4 * 16 + lr;
      const f16x8 kf0 = swzread(&Kt[cur][0][0], r, lg);
      const f16x8 kf1 = swzread(&Kt[cur][0][0], r, lg + 4);
      f32x4 s = mfma16(kf0, qf0, f32x4{0.f, 0.f, 0.f, 0.f});
      sa[t4] = mfma16(kf1, qf1, s);
    }
    __builtin_amdgcn_s_setprio(0);

    // online softmax (per-lane q-row), defer-max with THR=8 (base-2)
    float t01 = fmaxf(fmaxf(sa[0][0], sa[0][1]), fmaxf(sa[0][2], sa[0][3]));
    float t23 = fmaxf(fmaxf(sa[1][0], sa[1][1]), fmaxf(sa[1][2], sa[1][3]));
    float t45 = fmaxf(fmaxf(sa[2][0], sa[2][1]), fmaxf(sa[2][2], sa[2][3]));
    float t67 = fmaxf(fmaxf(sa[3][0], sa[3][1]), fmaxf(sa[3][2], sa[3][3]));
    float tm = fmaxf(fmaxf(t01, t23), fmaxf(t45, t67));
    tm = fmaxf(tm, __shfl_xor(tm, 16));
    tm = fmaxf(tm, __shfl_xor(tm, 32));

    // negligible-tile skip: whole tile < 2^-24 relative to running max
    if (__all(tm < mr - 24.0f)) continue;

    if (__any(tm > mr + 8.0f)) {  // wave-uniform rescale
      const float nm = fmaxf(mr, tm);
      const float corr = exp2f(mr - nm);
      mr = nm;
      lsum *= corr;
      float cb4[4];
#pragma unroll
      for (int i = 0; i < 4; ++i)
        cb4[i] = __shfl(corr, (l & 48) + ((l >> 4) << 2) + i);
#pragma unroll
      for (int n = 0; n < 4; ++n)
#pragma unroll
        for (int i = 0; i < 4; ++i) oacc[n][i] *= cb4[i];
    }

    // P + PV in two 32-kv halves through the shared half-buffer
    float ts = 0.f;
#pragma unroll
    for (int H = 0; H < 2; ++H) {
#pragma unroll
      for (int th = 0; th < 2; ++th) {
        const int t4 = 2 * H + th;
        f16x4 pp;
#pragma unroll
        for (int i = 0; i < 4; ++i) {
          const float p = exp2f(sa[t4][i] - mr);
          ts += p;
          pp[i] = (_Float16)p;
        }
        // P[q=lr][kv'=16*th+4*lg+i], 64B row, swizzled
        *(f16x4*)(plbase + lr * 64 + ((th * 32 + lg * 8) ^ plswz)) = pp;
      }
      // A-operand: P[q=lr][kv'=8*lg+j]
      const f16x8 aP = *(const f16x8*)(plbase + lr * 64 + ((lg * 16) ^ plswz));
      __builtin_amdgcn_s_setprio(1);
#pragma unroll
      for (int n = 0; n < 4; ++n) {
        const int d = n * 16 + lr;
        const f16x8 bv = swzread(&Vt[cur][0][0], d, lg + 4 * H);
        oacc[n] = mfma16(aP, bv, oacc[n]);
      }
      __builtin_amdgcn_s_setprio(0);
    }
    ts += __shfl_xor(ts, 16);
    ts += __shfl_xor(ts, 32);
    lsum += ts;
  }

  // epilogue: write per-row (m, lsum) — lanes 0-15 hold rows lr=l
  const size_t mlbase = ((size_t)kvh * 32 + bh) * SEQ + qb;
  if (l < 16) {
    marr[mlbase + l] = mr;
    larr[mlbase + l] = lsum;
  }
  // store unnormalized partial O as f16
  _Float16* opb = op + (size_t)kvh * BATCH * SEQ * EMB;
  const int b = bh >> 4, h = bh & 15;
#pragma unroll
  for (int n = 0; n < 4; ++n)
#pragma unroll
    for (int i = 0; i < 4; ++i) {
      const int row = qb + ((l >> 4) << 2) + i;
      opb[((size_t)b * SEQ + row) * EMB + h * HD_ + n * 16 + lr] =
          (_Float16)oacc[n][i];
    }
}

// ---------------- combine the two KV-halves ----------------
__global__ __launch_bounds__(256) void k_combine(const _Float16* __restrict__ op,
                                                 const float* __restrict__ marr,
                                                 const float* __restrict__ larr,
                                                 _Float16* __restrict__ ao) {
  const int idx = blockIdx.x * 256 + threadIdx.x;  // [0, B*S*E/8)
  const int e8 = idx & 127;                        // EMB/8 = 128
  const size_t rs = (size_t)(idx >> 7);            // b*SEQ + s
  const int h = e8 >> 3;
  const int b = (int)(rs >> 11);
  const size_t s = rs & (SEQ - 1);
  const size_t mi = ((size_t)b * NH + h) * SEQ + s;
  const float m1 = marr[mi], l1 = larr[mi];
  const float m2 = marr[(size_t)32 * SEQ + mi], l2 = larr[(size_t)32 * SEQ + mi];
  const float mx = fmaxf(m1, m2);
  const float w1 = exp2f(m1 - mx), w2 = exp2f(m2 - mx);
  const float inv = 1.0f / (l1 * w1 + l2 * w2);
  const f16x8 o1 = ((const f16x8*)op)[idx];
  const f16x8 o2 = ((const f16x8*)op)[idx + (BATCH * SEQ * EMB / 8)];
  f16x8 r;
#pragma unroll
  for (int j = 0; j < 8; ++j)
    r[j] = (_Float16)(((float)o1[j] * w1 + (float)o2[j] * w2) * inv);
  ((f16x8*)ao)[idx] = r;
}

extern "C" void kernel_launch(void* const* d_in, const int* in_sizes, int n_in,
                              void* d_out, int out_size, void* d_ws, size_t ws_size,
                              hipStream_t stream) {
  const float* query = (const float*)d_in[0];
  const float* Wqkv = (const float*)d_in[3];
  const float* bqkv = (const float*)d_in[4];
  const float* Wproj = (const float*)d_in[5];
  const float* bproj = (const float*)d_in[6];
  float* out = (float*)d_out;

  char* ws = (char*)d_ws;
  const size_t MB = 1024 * 1024;
  _Float16* q_f16   = (_Float16*)(ws + 0);         // 8MB; dead after QKV GEMM
  _Float16* Wqkv_t  = (_Float16*)(ws + 16 * MB);   // 6MB f16 (rows: q|k|v)
  _Float16* q_s     = (_Float16*)(ws + 24 * MB);   // 8MB [32][2048][64]
  _Float16* k_s     = (_Float16*)(ws + 32 * MB);   // 8MB
  _Float16* v_t     = (_Float16*)(ws + 40 * MB);   // 8MB [32][64][2048]
  _Float16* op      = (_Float16*)(ws + 0);         // 16MB partials (alias q_f16 + spare)
  _Float16* Wproj_t = (_Float16*)(ws + 48 * MB);   // 2MB
  float*    marr    = (float*)(ws + 50 * MB);      // 512KB [2][32][2048]
  float*    larr    = (float*)(ws + 50 * MB + 512 * 1024);  // 512KB
  _Float16* a_o     = (_Float16*)(ws + 51 * MB);   // 8MB

  const int M = BATCH * SEQ;  // 4096
  k_prep<<<dim3(8192), 256, 0, stream>>>(query, q_f16, Wqkv, Wqkv_t, Wproj, Wproj_t);
  k_gemm_qkv<<<dim3(24, M / 128), 256, 0, stream>>>(q_f16, Wqkv_t, bqkv, q_s, k_s, v_t);
  k_attn<<<dim3(1024), 512, 0, stream>>>(q_s, k_s, v_t, op, marr, larr);
  k_combine<<<dim3(BATCH * SEQ * EMB / 8 / 256), 256, 0, stream>>>(op, marr, larr, a_o);
  k_gemm_proj<<<dim3(EMB / 128, M / 128), 256, 0, stream>>>(a_o, Wproj_t, bproj, out);
}

// Round 16
// 147.915 us; speedup vs baseline: 1.0575x; 1.0415x over previous
//
#include <hip/hip_runtime.h>
#include <hip/hip_bf16.h>
#include <stdint.h>

typedef __attribute__((ext_vector_type(8))) _Float16 f16x8;
typedef __attribute__((ext_vector_type(4))) _Float16 f16x4;
typedef __attribute__((ext_vector_type(4))) float f32x4;

static constexpr int BATCH = 2;
static constexpr int SEQ = 2048;
static constexpr int EMB = 1024;
static constexpr int NH = 16;
static constexpr int HD_ = 64;

#define AS1 __attribute__((address_space(1)))
#define AS3 __attribute__((address_space(3)))

__device__ __forceinline__ void gload_lds16(const void* g, void* l) {
  __builtin_amdgcn_global_load_lds((const AS1 uint32_t*)g, (AS3 uint32_t*)l, 16, 0, 0);
}

__device__ __forceinline__ f32x4 mfma16(f16x8 a, f16x8 b, f32x4 c) {
  return __builtin_amdgcn_mfma_f32_16x16x32_f16(a, b, c, 0, 0, 0);
}

// swizzled 16B-block read from a 128B-row LDS tile: byte ^= (row&7)<<4
__device__ __forceinline__ f16x8 swzread(const _Float16* base, int row, int blk) {
  return *(const f16x8*)((const char*)base + row * 128 +
                         ((blk * 16) ^ ((row & 7) << 4)));
}

// ---------------- merged prep: convert q -> f16, transpose Wqkv (perm), Wproj --------
// blocks [0,4096): q convert; [4096,7168): Wqkv transpose+perm; [7168,8192): Wproj.
__global__ __launch_bounds__(256) void k_prep(const float* __restrict__ q,
                                              _Float16* __restrict__ qo,
                                              const float* __restrict__ wqkv,
                                              _Float16* __restrict__ wqkvo,
                                              const float* __restrict__ wproj,
                                              _Float16* __restrict__ wprojo) {
  __shared__ float tile[32][33];
  const int blk = blockIdx.x;
  const int t = threadIdx.x;
  if (blk < 4096) {  // convert: 4096*256 float4 = 4096*1024 floats
    const int idx = blk * 256 + t;
    float4 v = reinterpret_cast<const float4*>(q)[idx];
    const float* f = reinterpret_cast<const float*>(&v);
    _Float16 h[4];
#pragma unroll
    for (int i = 0; i < 4; ++i) h[i] = (_Float16)f[i];
    reinterpret_cast<uint2*>(qo)[idx] = *reinterpret_cast<uint2*>(h);
    return;
  }
  const float* in;
  _Float16* out;
  int R, C, bx, by;
  bool perm;
  if (blk < 4096 + 3072) {  // Wqkv: grid (96, 32)
    const int lo = blk - 4096;
    bx = lo % 96;
    by = lo / 96;
    in = wqkv; out = wqkvo; R = 1024; C = 3072; perm = true;
  } else {  // Wproj: grid (32, 32)
    const int lo = blk - 7168;
    bx = lo & 31;
    by = lo >> 5;
    in = wproj; out = wprojo; R = 1024; C = 1024; perm = false;
  }
  const int tr = t >> 5, tc = t & 31;
  const int r0 = by * 32, c0 = bx * 32;
#pragma unroll
  for (int rr = 0; rr < 32; rr += 8)
    tile[tr + rr][tc] = in[(size_t)(r0 + tr + rr) * C + c0 + tc];
  __syncthreads();
#pragma unroll
  for (int rr = 0; rr < 32; rr += 8) {
    const int c = c0 + tr + rr;
    int d = c;
    if (perm) {  // columns -> [q(1024) | k(1024) | v(1024)]
      const int h = c / 192, r = c - h * 192;
      d = (r < 64) ? h * 64 + r
                   : (r < 128 ? 1024 + h * 64 + (r - 64) : 2048 + h * 64 + (r - 128));
    }
    out[(size_t)d * R + r0 + tc] = (_Float16)tile[tc][tr + rr];
  }
}

// ---------------- QKV GEMM: A f16[4096][1024] x Bt f16[3072][1024]^T, 1 MFMA ---------
// XCD-grouped launch (768 blocks, 768%8==0 bijective): xcd = id&7 owns 4
// contiguous m-panels x all 24 n-panels -> A-panels L2-resident per XCD.
// epilogue scatter: q_s f16 (x 8*log2e), k_s f16, v_t f16 transposed (f16x4 stores)
__global__ __launch_bounds__(256) void k_gemm_qkv(const _Float16* __restrict__ A,
                                                  const _Float16* __restrict__ Bt,
                                                  const float* __restrict__ bias,
                                                  _Float16* __restrict__ oq,
                                                  _Float16* __restrict__ ok,
                                                  _Float16* __restrict__ ov) {
  constexpr int K = EMB;
  __shared__ _Float16 As[2][128 * 32];
  __shared__ _Float16 Bs[2][128 * 32];
  const int t = threadIdx.x;
  const int l = t & 63, w = t >> 6;
  const int lr = l & 15, lg = l >> 4;
  const int wr = w >> 1, wc = w & 1;
  // XCD swizzle: id -> (xcd, wg); xcd gets m-panels [xcd*4, xcd*4+4)
  const int id = blockIdx.x;
  const int xcd = id & 7, wg = id >> 3;       // wg in [0,96)
  const int m0 = (xcd * 4 + wg / 24) * 128;
  const int n0 = (wg % 24) * 128;

  auto stage = [&](int buf, int k0) {
#pragma unroll
    for (int j = 0; j < 2; ++j) {
      const int c = t + 256 * j;
      const int row = c >> 2, cb = c & 3;
      gload_lds16(A + (size_t)(m0 + row) * K + k0 + cb * 8, &As[buf][c * 8]);
      gload_lds16(Bt + (size_t)(n0 + row) * K + k0 + cb * 8, &Bs[buf][c * 8]);
    }
  };

  f32x4 acc[4][4];
#pragma unroll
  for (int m = 0; m < 4; ++m)
#pragma unroll
    for (int n = 0; n < 4; ++n) acc[m][n] = f32x4{0.f, 0.f, 0.f, 0.f};

  stage(0, 0);
  const int NT = K / 32;
  int cur = 0;
  for (int kt = 0; kt < NT; ++kt) {
    __syncthreads();
    if (kt + 1 < NT) stage(cur ^ 1, (kt + 1) * 32);
    f16x8 af[4], bf[4];
#pragma unroll
    for (int m = 0; m < 4; ++m)
      af[m] = *(const f16x8*)&As[cur][(wr * 64 + m * 16 + lr) * 32 + lg * 8];
#pragma unroll
    for (int n = 0; n < 4; ++n)
      bf[n] = *(const f16x8*)&Bs[cur][(wc * 64 + n * 16 + lr) * 32 + lg * 8];
#pragma unroll
    for (int m = 0; m < 4; ++m)
#pragma unroll
      for (int n = 0; n < 4; ++n) acc[m][n] = mfma16(af[m], bf[n], acc[m][n]);
    cur ^= 1;
  }

  const int sec = n0 >> 10;  // 0=q 1=k 2=v (block-uniform)
#pragma unroll
  for (int m = 0; m < 4; ++m) {
#pragma unroll
    for (int n = 0; n < 4; ++n) {
      const int col = n0 + wc * 64 + n * 16 + lr;
      const int cc = col & 1023;
      const int h = cc >> 6, r = cc & 63;
      const float bv = bias[h * 192 + sec * 64 + r];
      const int row0 = m0 + wr * 64 + m * 16 + lg * 4;
      const int b = row0 >> 11, s0 = row0 & (SEQ - 1);
      if (sec == 2) {  // V^T: i -> s consecutive, 4-aligned -> one 8B store
        f16x4 vv;
#pragma unroll
        for (int i = 0; i < 4; ++i) vv[i] = (_Float16)(acc[m][n][i] + bv);
        *(f16x4*)&ov[(((size_t)b * NH + h) * HD_ + r) * SEQ + s0] = vv;
      } else {
#pragma unroll
        for (int i = 0; i < 4; ++i) {
          const float v = acc[m][n][i] + bv;
          const size_t dst = (((size_t)b * NH + h) * SEQ + s0 + i) * HD_ + r;
          if (sec == 0)
            oq[dst] = (_Float16)(v * 11.5415603f);  // 8*log2(e) folded
          else
            ok[dst] = (_Float16)v;
        }
      }
    }
  }
}

// ---------------- proj GEMM: a_o f16 x Wproj_t f16^T -> f32 + bias ----------------
__global__ __launch_bounds__(256) void k_gemm_proj(const _Float16* __restrict__ A,
                                                   const _Float16* __restrict__ Bt,
                                                   const float* __restrict__ bias,
                                                   float* __restrict__ of) {
  constexpr int K = EMB, N = EMB;
  __shared__ _Float16 As[2][128 * 32];
  __shared__ _Float16 Bs[2][128 * 32];
  const int t = threadIdx.x;
  const int l = t & 63, w = t >> 6;
  const int lr = l & 15, lg = l >> 4;
  const int wr = w >> 1, wc = w & 1;
  const int m0 = blockIdx.y * 128, n0 = blockIdx.x * 128;

  auto stage = [&](int buf, int k0) {
#pragma unroll
    for (int j = 0; j < 2; ++j) {
      const int c = t + 256 * j;
      const int row = c >> 2, cb = c & 3;
      gload_lds16(A + (size_t)(m0 + row) * K + k0 + cb * 8, &As[buf][c * 8]);
      gload_lds16(Bt + (size_t)(n0 + row) * K + k0 + cb * 8, &Bs[buf][c * 8]);
    }
  };

  f32x4 acc[4][4];
#pragma unroll
  for (int m = 0; m < 4; ++m)
#pragma unroll
    for (int n = 0; n < 4; ++n) acc[m][n] = f32x4{0.f, 0.f, 0.f, 0.f};

  stage(0, 0);
  const int NT = K / 32;
  int cur = 0;
  for (int kt = 0; kt < NT; ++kt) {
    __syncthreads();
    if (kt + 1 < NT) stage(cur ^ 1, (kt + 1) * 32);
    f16x8 af[4], bf[4];
#pragma unroll
    for (int m = 0; m < 4; ++m)
      af[m] = *(const f16x8*)&As[cur][(wr * 64 + m * 16 + lr) * 32 + lg * 8];
#pragma unroll
    for (int n = 0; n < 4; ++n)
      bf[n] = *(const f16x8*)&Bs[cur][(wc * 64 + n * 16 + lr) * 32 + lg * 8];
#pragma unroll
    for (int m = 0; m < 4; ++m)
#pragma unroll
      for (int n = 0; n < 4; ++n) acc[m][n] = mfma16(af[m], bf[n], acc[m][n]);
    cur ^= 1;
  }

#pragma unroll
  for (int m = 0; m < 4; ++m)
#pragma unroll
    for (int n = 0; n < 4; ++n)
#pragma unroll
      for (int i = 0; i < 4; ++i) {
        const int row = m0 + wr * 64 + m * 16 + lg * 4 + i;
        const int col = n0 + wc * 64 + n * 16 + lr;
        of[(size_t)row * N + col] = acc[m][n][i] + bias[col];
      }
}

// ---------------- flash attention, single-pass (no KV-split) ----------------
// grid 512 = (bh, 128 q-rows); 512 threads; 40KB LDS (P half-buffer).
// R15 body minus split: full 2048-kv sweep per block, epilogue normalizes and
// writes a_o directly (no combine). T21 swizzle; defer-max THR=8; neg-tile skip.
__global__ __launch_bounds__(512) void k_attn(const _Float16* __restrict__ qs,
                                              const _Float16* __restrict__ ks,
                                              const _Float16* __restrict__ vt,
                                              _Float16* __restrict__ ao) {
  __shared__ _Float16 Kt[2][64][64];    // [buf][kv][d]   swizzled rows (128B)
  __shared__ _Float16 Vt[2][64][64];    // [buf][d][kv]   swizzled rows
  __shared__ _Float16 Plh[8][16][32];   // per-wave P half [q][kv'], 64B rows
  const int t = threadIdx.x;
  const int l = t & 63, w = t >> 6;          // w in [0,8)
  const int lr = l & 15, lg = l >> 4;
  // XCD-grouping: id&7 -> XCD; per XCD: 4 heads x 16 q-blocks
  const int id = blockIdx.x;
  const int xc = id & 7, m_ = id >> 3;       // m_ in [0,64)
  const int bh = xc + 8 * (m_ >> 4);         // 4 heads per XCD
  const int qb = (m_ & 15) * 128 + w * 16;   // 128 q-rows per block

  // Q fragments (B-operand: n=q=lr, k=d)
  const size_t qoff = ((size_t)bh * SEQ + qb + lr) * HD_;
  const f16x8 qf0 = *(const f16x8*)(qs + qoff + lg * 8);
  const f16x8 qf1 = *(const f16x8*)(qs + qoff + 32 + lg * 8);

  const _Float16* kbase = ks + (size_t)bh * SEQ * HD_;
  const _Float16* vbase = vt + (size_t)bh * HD_ * SEQ;

  // async staging: 512 threads cover the 64x64 tile in one pass each for K,V.
  // LDS dest linear (DMA rule); global SOURCE block pre-swizzled (T21).
  const int srow = t >> 3, scb = t & 7;      // srow in [0,64)
  auto stage = [&](const int buf, const int kv0) {
    gload_lds16(kbase + (size_t)(kv0 + srow) * HD_ + (scb ^ (srow & 7)) * 8,
                &Kt[buf][srow][scb * 8]);
    gload_lds16(vbase + (size_t)srow * SEQ + kv0 + (scb ^ (srow & 7)) * 8,
                &Vt[buf][srow][scb * 8]);
  };

  stage(0, 0);

  float mr = -1e30f, lsum = 0.f;
  f32x4 oacc[4];
#pragma unroll
  for (int n = 0; n < 4; ++n) oacc[n] = f32x4{0.f, 0.f, 0.f, 0.f};

  char* plbase = (char*)&Plh[w][0][0];
  const int plswz = ((lr >> 1) & 3) << 4;    // 64B-row bank swizzle

  const int NT = SEQ / 64;  // 32 tiles
  for (int it = 0; it < NT; ++it) {
    const int cur = it & 1;
    __syncthreads();  // drains vmcnt: buf[cur] DMA complete; prev reads done
    if (it + 1 < NT) stage(cur ^ 1, (it + 1) * 64);

    // S^T = K Q^T : lane holds S[kv=16*t4+4*lg+i][q=lr]   (base-2 logits)
    f32x4 sa[4];
    __builtin_amdgcn_s_setprio(1);
#pragma unroll
    for (int t4 = 0; t4 < 4; ++t4) {
      const int r = t4 * 16 + lr;
      const f16x8 kf0 = swzread(&Kt[cur][0][0], r, lg);
      const f16x8 kf1 = swzread(&Kt[cur][0][0], r, lg + 4);
      f32x4 s = mfma16(kf0, qf0, f32x4{0.f, 0.f, 0.f, 0.f});
      sa[t4] = mfma16(kf1, qf1, s);
    }
    __builtin_amdgcn_s_setprio(0);

    // online softmax (per-lane q-row), defer-max with THR=8 (base-2)
    float t01 = fmaxf(fmaxf(sa[0][0], sa[0][1]), fmaxf(sa[0][2], sa[0][3]));
    float t23 = fmaxf(fmaxf(sa[1][0], sa[1][1]), fmaxf(sa[1][2], sa[1][3]));
    float t45 = fmaxf(fmaxf(sa[2][0], sa[2][1]), fmaxf(sa[2][2], sa[2][3]));
    float t67 = fmaxf(fmaxf(sa[3][0], sa[3][1]), fmaxf(sa[3][2], sa[3][3]));
    float tm = fmaxf(fmaxf(t01, t23), fmaxf(t45, t67));
    tm = fmaxf(tm, __shfl_xor(tm, 16));
    tm = fmaxf(tm, __shfl_xor(tm, 32));

    // negligible-tile skip: whole tile < 2^-24 relative to running max
    if (__all(tm < mr - 24.0f)) continue;

    if (__any(tm > mr + 8.0f)) {  // wave-uniform rescale
      const float nm = fmaxf(mr, tm);
      const float corr = exp2f(mr - nm);
      mr = nm;
      lsum *= corr;
      float cb4[4];
#pragma unroll
      for (int i = 0; i < 4; ++i)
        cb4[i] = __shfl(corr, (l & 48) + ((l >> 4) << 2) + i);
#pragma unroll
      for (int n = 0; n < 4; ++n)
#pragma unroll
        for (int i = 0; i < 4; ++i) oacc[n][i] *= cb4[i];
    }

    // P + PV in two 32-kv halves through the shared half-buffer
    float ts = 0.f;
#pragma unroll
    for (int H = 0; H < 2; ++H) {
#pragma unroll
      for (int th = 0; th < 2; ++th) {
        const int t4 = 2 * H + th;
        f16x4 pp;
#pragma unroll
        for (int i = 0; i < 4; ++i) {
          const float p = exp2f(sa[t4][i] - mr);
          ts += p;
          pp[i] = (_Float16)p;
        }
        // P[q=lr][kv'=16*th+4*lg+i], 64B row, swizzled
        *(f16x4*)(plbase + lr * 64 + ((th * 32 + lg * 8) ^ plswz)) = pp;
      }
      // A-operand: P[q=lr][kv'=8*lg+j]
      const f16x8 aP = *(const f16x8*)(plbase + lr * 64 + ((lg * 16) ^ plswz));
      __builtin_amdgcn_s_setprio(1);
#pragma unroll
      for (int n = 0; n < 4; ++n) {
        const int d = n * 16 + lr;
        const f16x8 bv = swzread(&Vt[cur][0][0], d, lg + 4 * H);
        oacc[n] = mfma16(aP, bv, oacc[n]);
      }
      __builtin_amdgcn_s_setprio(0);
    }
    ts += __shfl_xor(ts, 16);
    ts += __shfl_xor(ts, 32);
    lsum += ts;
  }

  // epilogue: fetch lsum for q=4*lg+i, normalize, store f16 to a_o
  float ls4[4];
#pragma unroll
  for (int i = 0; i < 4; ++i)
    ls4[i] = __shfl(lsum, (l & 48) + ((l >> 4) << 2) + i);
  const int b = bh >> 4, h = bh & 15;
#pragma unroll
  for (int n = 0; n < 4; ++n)
#pragma unroll
    for (int i = 0; i < 4; ++i) {
      const int row = qb + ((l >> 4) << 2) + i;
      ao[((size_t)b * SEQ + row) * EMB + h * HD_ + n * 16 + lr] =
          (_Float16)(oacc[n][i] / ls4[i]);
    }
}

extern "C" void kernel_launch(void* const* d_in, const int* in_sizes, int n_in,
                              void* d_out, int out_size, void* d_ws, size_t ws_size,
                              hipStream_t stream) {
  const float* query = (const float*)d_in[0];
  const float* Wqkv = (const float*)d_in[3];
  const float* bqkv = (const float*)d_in[4];
  const float* Wproj = (const float*)d_in[5];
  const float* bproj = (const float*)d_in[6];
  float* out = (float*)d_out;

  char* ws = (char*)d_ws;
  const size_t MB = 1024 * 1024;
  _Float16* q_f16   = (_Float16*)(ws + 0);         // 8MB; dead after QKV GEMM
  _Float16* Wqkv_t  = (_Float16*)(ws + 16 * MB);   // 6MB f16 (rows: q|k|v)
  _Float16* q_s     = (_Float16*)(ws + 24 * MB);   // 8MB [32][2048][64]
  _Float16* k_s     = (_Float16*)(ws + 32 * MB);   // 8MB
  _Float16* v_t     = (_Float16*)(ws + 40 * MB);   // 8MB [32][64][2048]
  _Float16* Wproj_t = (_Float16*)(ws + 48 * MB);   // 2MB
  _Float16* a_o     = (_Float16*)(ws + 51 * MB);   // 8MB

  const int M = BATCH * SEQ;  // 4096
  k_prep<<<dim3(8192), 256, 0, stream>>>(query, q_f16, Wqkv, Wqkv_t, Wproj, Wproj_t);
  k_gemm_qkv<<<dim3(768), 256, 0, stream>>>(q_f16, Wqkv_t, bqkv, q_s, k_s, v_t);
  k_attn<<<dim3(512), 512, 0, stream>>>(q_s, k_s, v_t, a_o);
  k_gemm_proj<<<dim3(EMB / 128, M / 128), 256, 0, stream>>>(a_o, Wproj_t, bproj, out);
}

// Round 17
// 146.047 us; speedup vs baseline: 1.0711x; 1.0128x over previous
//
#include <hip/hip_runtime.h>
#include <hip/hip_bf16.h>
#include <stdint.h>

typedef __attribute__((ext_vector_type(8))) _Float16 f16x8;
typedef __attribute__((ext_vector_type(4))) _Float16 f16x4;
typedef __attribute__((ext_vector_type(4))) float f32x4;

static constexpr int BATCH = 2;
static constexpr int SEQ = 2048;
static constexpr int EMB = 1024;
static constexpr int NH = 16;
static constexpr int HD_ = 64;

#define AS1 __attribute__((address_space(1)))
#define AS3 __attribute__((address_space(3)))

__device__ __forceinline__ void gload_lds16(const void* g, void* l) {
  __builtin_amdgcn_global_load_lds((const AS1 uint32_t*)g, (AS3 uint32_t*)l, 16, 0, 0);
}

__device__ __forceinline__ f32x4 mfma16(f16x8 a, f16x8 b, f32x4 c) {
  return __builtin_amdgcn_mfma_f32_16x16x32_f16(a, b, c, 0, 0, 0);
}

// swizzled 16B-block read from a 128B-row LDS tile: byte ^= (row&7)<<4
__device__ __forceinline__ f16x8 swzread(const _Float16* base, int row, int blk) {
  return *(const f16x8*)((const char*)base + row * 128 +
                         ((blk * 16) ^ ((row & 7) << 4)));
}

// ---------------- merged prep: convert q -> f16, transpose Wqkv (perm), Wproj --------
// blocks [0,4096): q convert; [4096,7168): Wqkv transpose+perm; [7168,8192): Wproj.
__global__ __launch_bounds__(256) void k_prep(const float* __restrict__ q,
                                              _Float16* __restrict__ qo,
                                              const float* __restrict__ wqkv,
                                              _Float16* __restrict__ wqkvo,
                                              const float* __restrict__ wproj,
                                              _Float16* __restrict__ wprojo) {
  __shared__ float tile[32][33];
  const int blk = blockIdx.x;
  const int t = threadIdx.x;
  if (blk < 4096) {  // convert: 4096*256 float4 = 4096*1024 floats
    const int idx = blk * 256 + t;
    float4 v = reinterpret_cast<const float4*>(q)[idx];
    const float* f = reinterpret_cast<const float*>(&v);
    _Float16 h[4];
#pragma unroll
    for (int i = 0; i < 4; ++i) h[i] = (_Float16)f[i];
    reinterpret_cast<uint2*>(qo)[idx] = *reinterpret_cast<uint2*>(h);
    return;
  }
  const float* in;
  _Float16* out;
  int R, C, bx, by;
  bool perm;
  if (blk < 4096 + 3072) {  // Wqkv: grid (96, 32)
    const int lo = blk - 4096;
    bx = lo % 96;
    by = lo / 96;
    in = wqkv; out = wqkvo; R = 1024; C = 3072; perm = true;
  } else {  // Wproj: grid (32, 32)
    const int lo = blk - 7168;
    bx = lo & 31;
    by = lo >> 5;
    in = wproj; out = wprojo; R = 1024; C = 1024; perm = false;
  }
  const int tr = t >> 5, tc = t & 31;
  const int r0 = by * 32, c0 = bx * 32;
#pragma unroll
  for (int rr = 0; rr < 32; rr += 8)
    tile[tr + rr][tc] = in[(size_t)(r0 + tr + rr) * C + c0 + tc];
  __syncthreads();
#pragma unroll
  for (int rr = 0; rr < 32; rr += 8) {
    const int c = c0 + tr + rr;
    int d = c;
    if (perm) {  // columns -> [q(1024) | k(1024) | v(1024)]
      const int h = c / 192, r = c - h * 192;
      d = (r < 64) ? h * 64 + r
                   : (r < 128 ? 1024 + h * 64 + (r - 64) : 2048 + h * 64 + (r - 128));
    }
    out[(size_t)d * R + r0 + tc] = (_Float16)tile[tc][tr + rr];
  }
}

// ---------------- QKV GEMM: A f16[4096][1024] x Bt f16[3072][1024]^T, 1 MFMA ---------
// XCD swizzle (768 blocks, bijective): xcd owns 8 m-panels x 12 n-panels,
// swept in 2m x 12n sub-chunks -> ~3.5MB L2 working set per XCD.
// epilogue scatter: q_s f16 (x 8*log2e), k_s f16, v_t f16 transposed (f16x4 stores)
__global__ __launch_bounds__(256) void k_gemm_qkv(const _Float16* __restrict__ A,
                                                  const _Float16* __restrict__ Bt,
                                                  const float* __restrict__ bias,
                                                  _Float16* __restrict__ oq,
                                                  _Float16* __restrict__ ok,
                                                  _Float16* __restrict__ ov) {
  constexpr int K = EMB;
  __shared__ _Float16 As[2][128 * 32];
  __shared__ _Float16 Bs[2][128 * 32];
  const int t = threadIdx.x;
  const int l = t & 63, w = t >> 6;
  const int lr = l & 15, lg = l >> 4;
  const int wr = w >> 1, wc = w & 1;
  // id -> (xcd, wg): xcd = (mq, ng); wg sweeps mi-major-after-ni (2m x 12n chunks)
  const int id = blockIdx.x;
  const int xcd = id & 7, wg = id >> 3;       // wg in [0,96)
  const int mq = xcd & 3, ng = xcd >> 2;      // 4 m-groups x 2 n-groups
  const int mi = wg / 12, ni = wg % 12;       // mi in [0,8), ni in [0,12)
  const int m0 = (mq * 8 + mi) * 128;
  const int n0 = (ng * 12 + ni) * 128;

  auto stage = [&](int buf, int k0) {
#pragma unroll
    for (int j = 0; j < 2; ++j) {
      const int c = t + 256 * j;
      const int row = c >> 2, cb = c & 3;
      gload_lds16(A + (size_t)(m0 + row) * K + k0 + cb * 8, &As[buf][c * 8]);
      gload_lds16(Bt + (size_t)(n0 + row) * K + k0 + cb * 8, &Bs[buf][c * 8]);
    }
  };

  f32x4 acc[4][4];
#pragma unroll
  for (int m = 0; m < 4; ++m)
#pragma unroll
    for (int n = 0; n < 4; ++n) acc[m][n] = f32x4{0.f, 0.f, 0.f, 0.f};

  stage(0, 0);
  const int NT = K / 32;
  int cur = 0;
  for (int kt = 0; kt < NT; ++kt) {
    __syncthreads();
    if (kt + 1 < NT) stage(cur ^ 1, (kt + 1) * 32);
    f16x8 af[4], bf[4];
#pragma unroll
    for (int m = 0; m < 4; ++m)
      af[m] = *(const f16x8*)&As[cur][(wr * 64 + m * 16 + lr) * 32 + lg * 8];
#pragma unroll
    for (int n = 0; n < 4; ++n)
      bf[n] = *(const f16x8*)&Bs[cur][(wc * 64 + n * 16 + lr) * 32 + lg * 8];
#pragma unroll
    for (int m = 0; m < 4; ++m)
#pragma unroll
      for (int n = 0; n < 4; ++n) acc[m][n] = mfma16(af[m], bf[n], acc[m][n]);
    cur ^= 1;
  }

  const int sec = n0 >> 10;  // 0=q 1=k 2=v (block-uniform)
#pragma unroll
  for (int m = 0; m < 4; ++m) {
#pragma unroll
    for (int n = 0; n < 4; ++n) {
      const int col = n0 + wc * 64 + n * 16 + lr;
      const int cc = col & 1023;
      const int h = cc >> 6, r = cc & 63;
      const float bv = bias[h * 192 + sec * 64 + r];
      const int row0 = m0 + wr * 64 + m * 16 + lg * 4;
      const int b = row0 >> 11, s0 = row0 & (SEQ - 1);
      if (sec == 2) {  // V^T: i -> s consecutive, 4-aligned -> one 8B store
        f16x4 vv;
#pragma unroll
        for (int i = 0; i < 4; ++i) vv[i] = (_Float16)(acc[m][n][i] + bv);
        *(f16x4*)&ov[(((size_t)b * NH + h) * HD_ + r) * SEQ + s0] = vv;
      } else {
#pragma unroll
        for (int i = 0; i < 4; ++i) {
          const float v = acc[m][n][i] + bv;
          const size_t dst = (((size_t)b * NH + h) * SEQ + s0 + i) * HD_ + r;
          if (sec == 0)
            oq[dst] = (_Float16)(v * 11.5415603f);  // 8*log2(e) folded
          else
            ok[dst] = (_Float16)v;
        }
      }
    }
  }
}

// ---------------- proj GEMM: a_o f16 x Wproj_t f16^T -> f32 + bias ----------------
// XCD swizzle (256 blocks, bijective): xcd owns 4 m-panels x all 8 n (~3MB).
__global__ __launch_bounds__(256) void k_gemm_proj(const _Float16* __restrict__ A,
                                                   const _Float16* __restrict__ Bt,
                                                   const float* __restrict__ bias,
                                                   float* __restrict__ of) {
  constexpr int K = EMB, N = EMB;
  __shared__ _Float16 As[2][128 * 32];
  __shared__ _Float16 Bs[2][128 * 32];
  const int t = threadIdx.x;
  const int l = t & 63, w = t >> 6;
  const int lr = l & 15, lg = l >> 4;
  const int wr = w >> 1, wc = w & 1;
  const int id = blockIdx.x;
  const int xcd = id & 7, wg = id >> 3;       // wg in [0,32)
  const int m0 = (xcd * 4 + wg / 8) * 128;
  const int n0 = (wg & 7) * 128;

  auto stage = [&](int buf, int k0) {
#pragma unroll
    for (int j = 0; j < 2; ++j) {
      const int c = t + 256 * j;
      const int row = c >> 2, cb = c & 3;
      gload_lds16(A + (size_t)(m0 + row) * K + k0 + cb * 8, &As[buf][c * 8]);
      gload_lds16(Bt + (size_t)(n0 + row) * K + k0 + cb * 8, &Bs[buf][c * 8]);
    }
  };

  f32x4 acc[4][4];
#pragma unroll
  for (int m = 0; m < 4; ++m)
#pragma unroll
    for (int n = 0; n < 4; ++n) acc[m][n] = f32x4{0.f, 0.f, 0.f, 0.f};

  stage(0, 0);
  const int NT = K / 32;
  int cur = 0;
  for (int kt = 0; kt < NT; ++kt) {
    __syncthreads();
    if (kt + 1 < NT) stage(cur ^ 1, (kt + 1) * 32);
    f16x8 af[4], bf[4];
#pragma unroll
    for (int m = 0; m < 4; ++m)
      af[m] = *(const f16x8*)&As[cur][(wr * 64 + m * 16 + lr) * 32 + lg * 8];
#pragma unroll
    for (int n = 0; n < 4; ++n)
      bf[n] = *(const f16x8*)&Bs[cur][(wc * 64 + n * 16 + lr) * 32 + lg * 8];
#pragma unroll
    for (int m = 0; m < 4; ++m)
#pragma unroll
      for (int n = 0; n < 4; ++n) acc[m][n] = mfma16(af[m], bf[n], acc[m][n]);
    cur ^= 1;
  }

#pragma unroll
  for (int m = 0; m < 4; ++m)
#pragma unroll
    for (int n = 0; n < 4; ++n)
#pragma unroll
      for (int i = 0; i < 4; ++i) {
        const int row = m0 + wr * 64 + m * 16 + lg * 4 + i;
        const int col = n0 + wc * 64 + n * 16 + lr;
        of[(size_t)row * N + col] = acc[m][n][i] + bias[col];
      }
}

// ---------------- flash attention, single-pass, full P buffer (R13 path) ------------
// grid 512 = (bh, 128 q-rows); 512 threads; 48KB LDS. T21 swizzle; defer-max
// THR=8 (base-2); negligible-tile skip. Epilogue normalizes, writes a_o.
__global__ __launch_bounds__(512) void k_attn(const _Float16* __restrict__ qs,
                                              const _Float16* __restrict__ ks,
                                              const _Float16* __restrict__ vt,
                                              _Float16* __restrict__ ao) {
  __shared__ _Float16 Kt[2][64][64];   // [buf][kv][d]   swizzled rows (128B)
  __shared__ _Float16 Vt[2][64][64];   // [buf][d][kv]   swizzled rows
  __shared__ _Float16 Pl[8][16][64];   // per-wave P [q][kv], swizzled rows
  const int t = threadIdx.x;
  const int l = t & 63, w = t >> 6;          // w in [0,8)
  const int lr = l & 15, lg = l >> 4;
  // XCD-grouping: id&7 -> XCD; per XCD: 4 heads x 16 q-blocks
  const int id = blockIdx.x;
  const int xc = id & 7, m_ = id >> 3;       // m_ in [0,64)
  const int bh = xc + 8 * (m_ >> 4);         // 4 heads per XCD
  const int qb = (m_ & 15) * 128 + w * 16;   // 128 q-rows per block

  // Q fragments (B-operand: n=q=lr, k=d)
  const size_t qoff = ((size_t)bh * SEQ + qb + lr) * HD_;
  const f16x8 qf0 = *(const f16x8*)(qs + qoff + lg * 8);
  const f16x8 qf1 = *(const f16x8*)(qs + qoff + 32 + lg * 8);

  const _Float16* kbase = ks + (size_t)bh * SEQ * HD_;
  const _Float16* vbase = vt + (size_t)bh * HD_ * SEQ;

  // async staging: 512 threads cover the 64x64 tile in one pass each for K,V.
  // LDS dest linear (DMA rule); global SOURCE block pre-swizzled (T21).
  const int srow = t >> 3, scb = t & 7;      // srow in [0,64)
  auto stage = [&](const int buf, const int kv0) {
    gload_lds16(kbase + (size_t)(kv0 + srow) * HD_ + (scb ^ (srow & 7)) * 8,
                &Kt[buf][srow][scb * 8]);
    gload_lds16(vbase + (size_t)srow * SEQ + kv0 + (scb ^ (srow & 7)) * 8,
                &Vt[buf][srow][scb * 8]);
  };

  stage(0, 0);

  float mr = -1e30f, lsum = 0.f;
  f32x4 oacc[4];
#pragma unroll
  for (int n = 0; n < 4; ++n) oacc[n] = f32x4{0.f, 0.f, 0.f, 0.f};

  const int NT = SEQ / 64;  // 32 tiles
  for (int it = 0; it < NT; ++it) {
    const int cur = it & 1;
    __syncthreads();  // drains vmcnt: buf[cur] DMA complete; prev reads done
    if (it + 1 < NT) stage(cur ^ 1, (it + 1) * 64);

    // S^T = K Q^T : lane holds S[kv=16*t4+4*lg+i][q=lr]   (base-2 logits)
    f32x4 sa[4];
    __builtin_amdgcn_s_setprio(1);
#pragma unroll
    for (int t4 = 0; t4 < 4; ++t4) {
      const int r = t4 * 16 + lr;
      const f16x8 kf0 = swzread(&Kt[cur][0][0], r, lg);
      const f16x8 kf1 = swzread(&Kt[cur][0][0], r, lg + 4);
      f32x4 s = mfma16(kf0, qf0, f32x4{0.f, 0.f, 0.f, 0.f});
      sa[t4] = mfma16(kf1, qf1, s);
    }
    __builtin_amdgcn_s_setprio(0);

    // online softmax (per-lane q-row), defer-max with THR=8 (base-2)
    float t01 = fmaxf(fmaxf(sa[0][0], sa[0][1]), fmaxf(sa[0][2], sa[0][3]));
    float t23 = fmaxf(fmaxf(sa[1][0], sa[1][1]), fmaxf(sa[1][2], sa[1][3]));
    float t45 = fmaxf(fmaxf(sa[2][0], sa[2][1]), fmaxf(sa[2][2], sa[2][3]));
    float t67 = fmaxf(fmaxf(sa[3][0], sa[3][1]), fmaxf(sa[3][2], sa[3][3]));
    float tm = fmaxf(fmaxf(t01, t23), fmaxf(t45, t67));
    tm = fmaxf(tm, __shfl_xor(tm, 16));
    tm = fmaxf(tm, __shfl_xor(tm, 32));

    // negligible-tile skip: whole tile < 2^-24 relative to running max
    if (__all(tm < mr - 24.0f)) continue;

    if (__any(tm > mr + 8.0f)) {  // wave-uniform rescale
      const float nm = fmaxf(mr, tm);
      const float corr = exp2f(mr - nm);
      mr = nm;
      lsum *= corr;
      float cb4[4];
#pragma unroll
      for (int i = 0; i < 4; ++i)
        cb4[i] = __shfl(corr, (l & 48) + ((l >> 4) << 2) + i);
#pragma unroll
      for (int n = 0; n < 4; ++n)
#pragma unroll
        for (int i = 0; i < 4; ++i) oacc[n][i] *= cb4[i];
    }

    float ts = 0.f;
    char* plbase = (char*)&Pl[w][0][0];
#pragma unroll
    for (int t4 = 0; t4 < 4; ++t4) {
      f16x4 pp;
#pragma unroll
      for (int i = 0; i < 4; ++i) {
        const float p = exp2f(sa[t4][i] - mr);
        ts += p;
        pp[i] = (_Float16)p;
      }
      // P[q=lr][kv=t4*16+lg*4+i], swizzled row (XOR bits 4-6, 8B aligned)
      *(f16x4*)(plbase + lr * 128 + ((t4 * 32 + lg * 8) ^ ((lr & 7) << 4))) = pp;
    }
    ts += __shfl_xor(ts, 16);
    ts += __shfl_xor(ts, 32);
    lsum += ts;

    // O += P V (A=P[q][kv], B=V^T[d][kv])
    const f16x8 aP0 = swzread(&Pl[w][0][0], lr, lg);
    const f16x8 aP1 = swzread(&Pl[w][0][0], lr, lg + 4);
    __builtin_amdgcn_s_setprio(1);
#pragma unroll
    for (int n = 0; n < 4; ++n) {
      const int d = n * 16 + lr;
      const f16x8 bv0 = swzread(&Vt[cur][0][0], d, lg);
      const f16x8 bv1 = swzread(&Vt[cur][0][0], d, lg + 4);
      oacc[n] = mfma16(aP0, bv0, oacc[n]);
      oacc[n] = mfma16(aP1, bv1, oacc[n]);
    }
    __builtin_amdgcn_s_setprio(0);
  }

  // epilogue: fetch lsum for q=4*lg+i, normalize, store f16 to a_o
  float ls4[4];
#pragma unroll
  for (int i = 0; i < 4; ++i)
    ls4[i] = __shfl(lsum, (l & 48) + ((l >> 4) << 2) + i);
  const int b = bh >> 4, h = bh & 15;
#pragma unroll
  for (int n = 0; n < 4; ++n)
#pragma unroll
    for (int i = 0; i < 4; ++i) {
      const int row = qb + ((l >> 4) << 2) + i;
      ao[((size_t)b * SEQ + row) * EMB + h * HD_ + n * 16 + lr] =
          (_Float16)(oacc[n][i] / ls4[i]);
    }
}

extern "C" void kernel_launch(void* const* d_in, const int* in_sizes, int n_in,
                              void* d_out, int out_size, void* d_ws, size_t ws_size,
                              hipStream_t stream) {
  const float* query = (const float*)d_in[0];
  const float* Wqkv = (const float*)d_in[3];
  const float* bqkv = (const float*)d_in[4];
  const float* Wproj = (const float*)d_in[5];
  const float* bproj = (const float*)d_in[6];
  float* out = (float*)d_out;

  char* ws = (char*)d_ws;
  const size_t MB = 1024 * 1024;
  _Float16* q_f16   = (_Float16*)(ws + 0);         // 8MB; dead after QKV GEMM
  _Float16* Wqkv_t  = (_Float16*)(ws + 16 * MB);   // 6MB f16 (rows: q|k|v)
  _Float16* q_s     = (_Float16*)(ws + 24 * MB);   // 8MB [32][2048][64]
  _Float16* k_s     = (_Float16*)(ws + 32 * MB);   // 8MB
  _Float16* v_t     = (_Float16*)(ws + 40 * MB);   // 8MB [32][64][2048]
  _Float16* Wproj_t = (_Float16*)(ws + 48 * MB);   // 2MB
  _Float16* a_o     = (_Float16*)(ws + 51 * MB);   // 8MB

  const int M = BATCH * SEQ;  // 4096
  k_prep<<<dim3(8192), 256, 0, stream>>>(query, q_f16, Wqkv, Wqkv_t, Wproj, Wproj_t);
  k_gemm_qkv<<<dim3(768), 256, 0, stream>>>(q_f16, Wqkv_t, bqkv, q_s, k_s, v_t);
  k_attn<<<dim3(512), 512, 0, stream>>>(q_s, k_s, v_t, a_o);
  k_gemm_proj<<<dim3(256), 256, 0, stream>>>(a_o, Wproj_t, bproj, out);
}

// Round 18
// 145.448 us; speedup vs baseline: 1.0755x; 1.0041x over previous
//
#include <hip/hip_runtime.h>
#include <hip/hip_bf16.h>
#include <stdint.h>

typedef __attribute__((ext_vector_type(8))) _Float16 f16x8;
typedef __attribute__((ext_vector_type(4))) _Float16 f16x4;
typedef __attribute__((ext_vector_type(4))) float f32x4;

static constexpr int BATCH = 2;
static constexpr int SEQ = 2048;
static constexpr int EMB = 1024;
static constexpr int NH = 16;
static constexpr int HD_ = 64;

#define AS1 __attribute__((address_space(1)))
#define AS3 __attribute__((address_space(3)))

__device__ __forceinline__ void gload_lds16(const void* g, void* l) {
  __builtin_amdgcn_global_load_lds((const AS1 uint32_t*)g, (AS3 uint32_t*)l, 16, 0, 0);
}

__device__ __forceinline__ f32x4 mfma16(f16x8 a, f16x8 b, f32x4 c) {
  return __builtin_amdgcn_mfma_f32_16x16x32_f16(a, b, c, 0, 0, 0);
}

// swizzled 16B-block read from a 128B-row LDS tile: byte ^= (row&7)<<4
__device__ __forceinline__ f16x8 swzread(const _Float16* base, int row, int blk) {
  return *(const f16x8*)((const char*)base + row * 128 +
                         ((blk * 16) ^ ((row & 7) << 4)));
}

// ---------------- merged prep: convert q -> f16, transpose Wqkv (perm), Wproj --------
// blocks [0,4096): q convert; [4096,7168): Wqkv transpose+perm; [7168,8192): Wproj.
__global__ __launch_bounds__(256) void k_prep(const float* __restrict__ q,
                                              _Float16* __restrict__ qo,
                                              const float* __restrict__ wqkv,
                                              _Float16* __restrict__ wqkvo,
                                              const float* __restrict__ wproj,
                                              _Float16* __restrict__ wprojo) {
  __shared__ float tile[32][33];
  const int blk = blockIdx.x;
  const int t = threadIdx.x;
  if (blk < 4096) {  // convert: 4096*256 float4 = 4096*1024 floats
    const int idx = blk * 256 + t;
    float4 v = reinterpret_cast<const float4*>(q)[idx];
    const float* f = reinterpret_cast<const float*>(&v);
    _Float16 h[4];
#pragma unroll
    for (int i = 0; i < 4; ++i) h[i] = (_Float16)f[i];
    reinterpret_cast<uint2*>(qo)[idx] = *reinterpret_cast<uint2*>(h);
    return;
  }
  const float* in;
  _Float16* out;
  int R, C, bx, by;
  bool perm;
  if (blk < 4096 + 3072) {  // Wqkv: grid (96, 32)
    const int lo = blk - 4096;
    bx = lo % 96;
    by = lo / 96;
    in = wqkv; out = wqkvo; R = 1024; C = 3072; perm = true;
  } else {  // Wproj: grid (32, 32)
    const int lo = blk - 7168;
    bx = lo & 31;
    by = lo >> 5;
    in = wproj; out = wprojo; R = 1024; C = 1024; perm = false;
  }
  const int tr = t >> 5, tc = t & 31;
  const int r0 = by * 32, c0 = bx * 32;
#pragma unroll
  for (int rr = 0; rr < 32; rr += 8)
    tile[tr + rr][tc] = in[(size_t)(r0 + tr + rr) * C + c0 + tc];
  __syncthreads();
#pragma unroll
  for (int rr = 0; rr < 32; rr += 8) {
    const int c = c0 + tr + rr;
    int d = c;
    if (perm) {  // columns -> [q(1024) | k(1024) | v(1024)]
      const int h = c / 192, r = c - h * 192;
      d = (r < 64) ? h * 64 + r
                   : (r < 128 ? 1024 + h * 64 + (r - 64) : 2048 + h * 64 + (r - 128));
    }
    out[(size_t)d * R + r0 + tc] = (_Float16)tile[tc][tr + rr];
  }
}

// ---------------- QKV GEMM: A f16[4096][1024] x Bt f16[3072][1024]^T, 1 MFMA ---------
// XCD swizzle (768 blocks, bijective): xcd owns 8 m-panels x 12 n-panels.
// epilogue scatter: q_s f16 (x 8*log2e), k_s f16, v_t f16 transposed (f16x4 stores)
__global__ __launch_bounds__(256) void k_gemm_qkv(const _Float16* __restrict__ A,
                                                  const _Float16* __restrict__ Bt,
                                                  const float* __restrict__ bias,
                                                  _Float16* __restrict__ oq,
                                                  _Float16* __restrict__ ok,
                                                  _Float16* __restrict__ ov) {
  constexpr int K = EMB;
  __shared__ _Float16 As[2][128 * 32];
  __shared__ _Float16 Bs[2][128 * 32];
  const int t = threadIdx.x;
  const int l = t & 63, w = t >> 6;
  const int lr = l & 15, lg = l >> 4;
  const int wr = w >> 1, wc = w & 1;
  const int id = blockIdx.x;
  const int xcd = id & 7, wg = id >> 3;       // wg in [0,96)
  const int mq = xcd & 3, ng = xcd >> 2;      // 4 m-groups x 2 n-groups
  const int mi = wg / 12, ni = wg % 12;       // mi in [0,8), ni in [0,12)
  const int m0 = (mq * 8 + mi) * 128;
  const int n0 = (ng * 12 + ni) * 128;

  auto stage = [&](int buf, int k0) {
#pragma unroll
    for (int j = 0; j < 2; ++j) {
      const int c = t + 256 * j;
      const int row = c >> 2, cb = c & 3;
      gload_lds16(A + (size_t)(m0 + row) * K + k0 + cb * 8, &As[buf][c * 8]);
      gload_lds16(Bt + (size_t)(n0 + row) * K + k0 + cb * 8, &Bs[buf][c * 8]);
    }
  };

  f32x4 acc[4][4];
#pragma unroll
  for (int m = 0; m < 4; ++m)
#pragma unroll
    for (int n = 0; n < 4; ++n) acc[m][n] = f32x4{0.f, 0.f, 0.f, 0.f};

  stage(0, 0);
  const int NT = K / 32;
  int cur = 0;
  for (int kt = 0; kt < NT; ++kt) {
    __syncthreads();
    if (kt + 1 < NT) stage(cur ^ 1, (kt + 1) * 32);
    f16x8 af[4], bf[4];
#pragma unroll
    for (int m = 0; m < 4; ++m)
      af[m] = *(const f16x8*)&As[cur][(wr * 64 + m * 16 + lr) * 32 + lg * 8];
#pragma unroll
    for (int n = 0; n < 4; ++n)
      bf[n] = *(const f16x8*)&Bs[cur][(wc * 64 + n * 16 + lr) * 32 + lg * 8];
#pragma unroll
    for (int m = 0; m < 4; ++m)
#pragma unroll
      for (int n = 0; n < 4; ++n) acc[m][n] = mfma16(af[m], bf[n], acc[m][n]);
    cur ^= 1;
  }

  const int sec = n0 >> 10;  // 0=q 1=k 2=v (block-uniform)
#pragma unroll
  for (int m = 0; m < 4; ++m) {
#pragma unroll
    for (int n = 0; n < 4; ++n) {
      const int col = n0 + wc * 64 + n * 16 + lr;
      const int cc = col & 1023;
      const int h = cc >> 6, r = cc & 63;
      const float bv = bias[h * 192 + sec * 64 + r];
      const int row0 = m0 + wr * 64 + m * 16 + lg * 4;
      const int b = row0 >> 11, s0 = row0 & (SEQ - 1);
      if (sec == 2) {  // V^T: i -> s consecutive, 4-aligned -> one 8B store
        f16x4 vv;
#pragma unroll
        for (int i = 0; i < 4; ++i) vv[i] = (_Float16)(acc[m][n][i] + bv);
        *(f16x4*)&ov[(((size_t)b * NH + h) * HD_ + r) * SEQ + s0] = vv;
      } else {
#pragma unroll
        for (int i = 0; i < 4; ++i) {
          const float v = acc[m][n][i] + bv;
          const size_t dst = (((size_t)b * NH + h) * SEQ + s0 + i) * HD_ + r;
          if (sec == 0)
            oq[dst] = (_Float16)(v * 11.5415603f);  // 8*log2(e) folded
          else
            ok[dst] = (_Float16)v;
        }
      }
    }
  }
}

// ---------------- proj GEMM: a_o f16 x Wproj_t f16^T -> f32 + bias ----------------
// XCD swizzle (256 blocks, bijective): xcd owns 4 m-panels x all 8 n (~3MB).
__global__ __launch_bounds__(256) void k_gemm_proj(const _Float16* __restrict__ A,
                                                   const _Float16* __restrict__ Bt,
                                                   const float* __restrict__ bias,
                                                   float* __restrict__ of) {
  constexpr int K = EMB, N = EMB;
  __shared__ _Float16 As[2][128 * 32];
  __shared__ _Float16 Bs[2][128 * 32];
  const int t = threadIdx.x;
  const int l = t & 63, w = t >> 6;
  const int lr = l & 15, lg = l >> 4;
  const int wr = w >> 1, wc = w & 1;
  const int id = blockIdx.x;
  const int xcd = id & 7, wg = id >> 3;       // wg in [0,32)
  const int m0 = (xcd * 4 + wg / 8) * 128;
  const int n0 = (wg & 7) * 128;

  auto stage = [&](int buf, int k0) {
#pragma unroll
    for (int j = 0; j < 2; ++j) {
      const int c = t + 256 * j;
      const int row = c >> 2, cb = c & 3;
      gload_lds16(A + (size_t)(m0 + row) * K + k0 + cb * 8, &As[buf][c * 8]);
      gload_lds16(Bt + (size_t)(n0 + row) * K + k0 + cb * 8, &Bs[buf][c * 8]);
    }
  };

  f32x4 acc[4][4];
#pragma unroll
  for (int m = 0; m < 4; ++m)
#pragma unroll
    for (int n = 0; n < 4; ++n) acc[m][n] = f32x4{0.f, 0.f, 0.f, 0.f};

  stage(0, 0);
  const int NT = K / 32;
  int cur = 0;
  for (int kt = 0; kt < NT; ++kt) {
    __syncthreads();
    if (kt + 1 < NT) stage(cur ^ 1, (kt + 1) * 32);
    f16x8 af[4], bf[4];
#pragma unroll
    for (int m = 0; m < 4; ++m)
      af[m] = *(const f16x8*)&As[cur][(wr * 64 + m * 16 + lr) * 32 + lg * 8];
#pragma unroll
    for (int n = 0; n < 4; ++n)
      bf[n] = *(const f16x8*)&Bs[cur][(wc * 64 + n * 16 + lr) * 32 + lg * 8];
#pragma unroll
    for (int m = 0; m < 4; ++m)
#pragma unroll
      for (int n = 0; n < 4; ++n) acc[m][n] = mfma16(af[m], bf[n], acc[m][n]);
    cur ^= 1;
  }

#pragma unroll
  for (int m = 0; m < 4; ++m)
#pragma unroll
    for (int n = 0; n < 4; ++n)
#pragma unroll
      for (int i = 0; i < 4; ++i) {
        const int row = m0 + wr * 64 + m * 16 + lg * 4 + i;
        const int col = n0 + wc * 64 + n * 16 + lr;
        of[(size_t)row * N + col] = acc[m][n][i] + bias[col];
      }
}

// ---------------- flash attention, single-pass, 3-buf counted-vmcnt pipeline --------
// grid 512 = (bh, 128 q-rows); 512 threads; 64KB LDS (3 K/V bufs + P).
// T3/T4 graft (m201 template): per tile {s_waitcnt vmcnt(2); s_barrier;
// issue stage(it+2); compute buf[it%3]}. Tile it+1's DMAs stay in flight
// across the barrier (old __syncthreads drained vmcnt(0) -> DMA-wait stall).
// Safety: buf[(it+2)%3] was read in iter it-1, completion guaranteed by the
// barrier; exactly 2 DMAs/thread/stage and no other VMEM ops in the loop, so
// vmcnt counts are exact; last iter uses vmcnt(0).
__global__ __launch_bounds__(512) void k_attn(const _Float16* __restrict__ qs,
                                              const _Float16* __restrict__ ks,
                                              const _Float16* __restrict__ vt,
                                              _Float16* __restrict__ ao) {
  __shared__ _Float16 Kt[3][64][64];   // [buf][kv][d]   swizzled rows (128B)
  __shared__ _Float16 Vt[3][64][64];   // [buf][d][kv]   swizzled rows
  __shared__ _Float16 Pl[8][16][64];   // per-wave P [q][kv], swizzled rows
  const int t = threadIdx.x;
  const int l = t & 63, w = t >> 6;          // w in [0,8)
  const int lr = l & 15, lg = l >> 4;
  // XCD-grouping: id&7 -> XCD; per XCD: 4 heads x 16 q-blocks
  const int id = blockIdx.x;
  const int xc = id & 7, m_ = id >> 3;       // m_ in [0,64)
  const int bh = xc + 8 * (m_ >> 4);         // 4 heads per XCD
  const int qb = (m_ & 15) * 128 + w * 16;   // 128 q-rows per block

  // Q fragments (B-operand: n=q=lr, k=d)
  const size_t qoff = ((size_t)bh * SEQ + qb + lr) * HD_;
  const f16x8 qf0 = *(const f16x8*)(qs + qoff + lg * 8);
  const f16x8 qf1 = *(const f16x8*)(qs + qoff + 32 + lg * 8);

  const _Float16* kbase = ks + (size_t)bh * SEQ * HD_;
  const _Float16* vbase = vt + (size_t)bh * HD_ * SEQ;

  // async staging: 512 threads cover the 64x64 tile in one pass each for K,V.
  // LDS dest linear (DMA rule); global SOURCE block pre-swizzled (T21).
  const int srow = t >> 3, scb = t & 7;      // srow in [0,64)
  auto stage = [&](const int buf, const int kv0) {
    gload_lds16(kbase + (size_t)(kv0 + srow) * HD_ + (scb ^ (srow & 7)) * 8,
                &Kt[buf][srow][scb * 8]);
    gload_lds16(vbase + (size_t)srow * SEQ + kv0 + (scb ^ (srow & 7)) * 8,
                &Vt[buf][srow][scb * 8]);
  };

  stage(0, 0);
  stage(1, 64);

  float mr = -1e30f, lsum = 0.f;
  f32x4 oacc[4];
#pragma unroll
  for (int n = 0; n < 4; ++n) oacc[n] = f32x4{0.f, 0.f, 0.f, 0.f};

  const int NT = SEQ / 64;  // 32 tiles
  int cur = 0;              // it % 3
  for (int it = 0; it < NT; ++it) {
    // wait own tile-it DMAs (2 newest may stay in flight), align all waves
    if (it == NT - 1)
      asm volatile("s_waitcnt vmcnt(0)" ::: "memory");
    else
      asm volatile("s_waitcnt vmcnt(2)" ::: "memory");
    __builtin_amdgcn_s_barrier();
    // issue tile it+2 into the buffer read in iter it-1 (barrier-protected)
    if (it + 2 < NT) {
      int nb = cur + 2;
      if (nb >= 3) nb -= 3;
      stage(nb, (it + 2) * 64);
    }

    // S^T = K Q^T : lane holds S[kv=16*t4+4*lg+i][q=lr]   (base-2 logits)
    f32x4 sa[4];
    __builtin_amdgcn_s_setprio(1);
#pragma unroll
    for (int t4 = 0; t4 < 4; ++t4) {
      const int r = t4 * 16 + lr;
      const f16x8 kf0 = swzread(&Kt[cur][0][0], r, lg);
      const f16x8 kf1 = swzread(&Kt[cur][0][0], r, lg + 4);
      f32x4 s = mfma16(kf0, qf0, f32x4{0.f, 0.f, 0.f, 0.f});
      sa[t4] = mfma16(kf1, qf1, s);
    }
    __builtin_amdgcn_s_setprio(0);

    // online softmax (per-lane q-row), defer-max with THR=8 (base-2)
    float t01 = fmaxf(fmaxf(sa[0][0], sa[0][1]), fmaxf(sa[0][2], sa[0][3]));
    float t23 = fmaxf(fmaxf(sa[1][0], sa[1][1]), fmaxf(sa[1][2], sa[1][3]));
    float t45 = fmaxf(fmaxf(sa[2][0], sa[2][1]), fmaxf(sa[2][2], sa[2][3]));
    float t67 = fmaxf(fmaxf(sa[3][0], sa[3][1]), fmaxf(sa[3][2], sa[3][3]));
    float tm = fmaxf(fmaxf(t01, t23), fmaxf(t45, t67));
    tm = fmaxf(tm, __shfl_xor(tm, 16));
    tm = fmaxf(tm, __shfl_xor(tm, 32));

    // negligible-tile skip: whole tile < 2^-24 relative to running max
    if (__all(tm < mr - 24.0f)) {
      cur = (cur + 1 == 3) ? 0 : cur + 1;
      continue;
    }

    if (__any(tm > mr + 8.0f)) {  // wave-uniform rescale
      const float nm = fmaxf(mr, tm);
      const float corr = exp2f(mr - nm);
      mr = nm;
      lsum *= corr;
      float cb4[4];
#pragma unroll
      for (int i = 0; i < 4; ++i)
        cb4[i] = __shfl(corr, (l & 48) + ((l >> 4) << 2) + i);
#pragma unroll
      for (int n = 0; n < 4; ++n)
#pragma unroll
        for (int i = 0; i < 4; ++i) oacc[n][i] *= cb4[i];
    }

    float ts = 0.f;
    char* plbase = (char*)&Pl[w][0][0];
#pragma unroll
    for (int t4 = 0; t4 < 4; ++t4) {
      f16x4 pp;
#pragma unroll
      for (int i = 0; i < 4; ++i) {
        const float p = exp2f(sa[t4][i] - mr);
        ts += p;
        pp[i] = (_Float16)p;
      }
      // P[q=lr][kv=t4*16+lg*4+i], swizzled row (XOR bits 4-6, 8B aligned)
      *(f16x4*)(plbase + lr * 128 + ((t4 * 32 + lg * 8) ^ ((lr & 7) << 4))) = pp;
    }
    ts += __shfl_xor(ts, 16);
    ts += __shfl_xor(ts, 32);
    lsum += ts;

    // O += P V (A=P[q][kv], B=V^T[d][kv])
    const f16x8 aP0 = swzread(&Pl[w][0][0], lr, lg);
    const f16x8 aP1 = swzread(&Pl[w][0][0], lr, lg + 4);
    __builtin_amdgcn_s_setprio(1);
#pragma unroll
    for (int n = 0; n < 4; ++n) {
      const int d = n * 16 + lr;
      const f16x8 bv0 = swzread(&Vt[cur][0][0], d, lg);
      const f16x8 bv1 = swzread(&Vt[cur][0][0], d, lg + 4);
      oacc[n] = mfma16(aP0, bv0, oacc[n]);
      oacc[n] = mfma16(aP1, bv1, oacc[n]);
    }
    __builtin_amdgcn_s_setprio(0);

    cur = (cur + 1 == 3) ? 0 : cur + 1;
  }

  // epilogue: fetch lsum for q=4*lg+i, normalize, store f16 to a_o
  float ls4[4];
#pragma unroll
  for (int i = 0; i < 4; ++i)
    ls4[i] = __shfl(lsum, (l & 48) + ((l >> 4) << 2) + i);
  const int b = bh >> 4, h = bh & 15;
#pragma unroll
  for (int n = 0; n < 4; ++n)
#pragma unroll
    for (int i = 0; i < 4; ++i) {
      const int row = qb + ((l >> 4) << 2) + i;
      ao[((size_t)b * SEQ + row) * EMB + h * HD_ + n * 16 + lr] =
          (_Float16)(oacc[n][i] / ls4[i]);
    }
}

extern "C" void kernel_launch(void* const* d_in, const int* in_sizes, int n_in,
                              void* d_out, int out_size, void* d_ws, size_t ws_size,
                              hipStream_t stream) {
  const float* query = (const float*)d_in[0];
  const float* Wqkv = (const float*)d_in[3];
  const float* bqkv = (const float*)d_in[4];
  const float* Wproj = (const float*)d_in[5];
  const float* bproj = (const float*)d_in[6];
  float* out = (float*)d_out;

  char* ws = (char*)d_ws;
  const size_t MB = 1024 * 1024;
  _Float16* q_f16   = (_Float16*)(ws + 0);         // 8MB; dead after QKV GEMM
  _Float16* Wqkv_t  = (_Float16*)(ws + 16 * MB);   // 6MB f16 (rows: q|k|v)
  _Float16* q_s     = (_Float16*)(ws + 24 * MB);   // 8MB [32][2048][64]
  _Float16* k_s     = (_Float16*)(ws + 32 * MB);   // 8MB
  _Float16* v_t     = (_Float16*)(ws + 40 * MB);   // 8MB [32][64][2048]
  _Float16* Wproj_t = (_Float16*)(ws + 48 * MB);   // 2MB
  _Float16* a_o     = (_Float16*)(ws + 51 * MB);   // 8MB

  const int M = BATCH * SEQ;  // 4096
  k_prep<<<dim3(8192), 256, 0, stream>>>(query, q_f16, Wqkv, Wqkv_t, Wproj, Wproj_t);
  k_gemm_qkv<<<dim3(768), 256, 0, stream>>>(q_f16, Wqkv_t, bqkv, q_s, k_s, v_t);
  k_attn<<<dim3(512), 512, 0, stream>>>(q_s, k_s, v_t, a_o);
  k_gemm_proj<<<dim3(256), 256, 0, stream>>>(a_o, Wproj_t, bproj, out);
}

// Round 19
// 145.145 us; speedup vs baseline: 1.0777x; 1.0021x over previous
//
#include <hip/hip_runtime.h>
#include <hip/hip_bf16.h>
#include <stdint.h>

typedef __attribute__((ext_vector_type(8))) _Float16 f16x8;
typedef __attribute__((ext_vector_type(4))) _Float16 f16x4;
typedef __attribute__((ext_vector_type(4))) float f32x4;

static constexpr int BATCH = 2;
static constexpr int SEQ = 2048;
static constexpr int EMB = 1024;
static constexpr int NH = 16;
static constexpr int HD_ = 64;

#define AS1 __attribute__((address_space(1)))
#define AS3 __attribute__((address_space(3)))

__device__ __forceinline__ void gload_lds16(const void* g, void* l) {
  __builtin_amdgcn_global_load_lds((const AS1 uint32_t*)g, (AS3 uint32_t*)l, 16, 0, 0);
}

__device__ __forceinline__ f32x4 mfma16(f16x8 a, f16x8 b, f32x4 c) {
  return __builtin_amdgcn_mfma_f32_16x16x32_f16(a, b, c, 0, 0, 0);
}

// swizzled 16B-block read from a 128B-row LDS tile: byte ^= (row&7)<<4
__device__ __forceinline__ f16x8 swzread(const _Float16* base, int row, int blk) {
  return *(const f16x8*)((const char*)base + row * 128 +
                         ((blk * 16) ^ ((row & 7) << 4)));
}

// ---------------- merged prep: convert q -> f16, transpose Wqkv (perm), Wproj --------
// blocks [0,4096): q convert; [4096,7168): Wqkv transpose+perm; [7168,8192): Wproj.
__global__ __launch_bounds__(256) void k_prep(const float* __restrict__ q,
                                              _Float16* __restrict__ qo,
                                              const float* __restrict__ wqkv,
                                              _Float16* __restrict__ wqkvo,
                                              const float* __restrict__ wproj,
                                              _Float16* __restrict__ wprojo) {
  __shared__ float tile[32][33];
  const int blk = blockIdx.x;
  const int t = threadIdx.x;
  if (blk < 4096) {  // convert: 4096*256 float4 = 4096*1024 floats
    const int idx = blk * 256 + t;
    float4 v = reinterpret_cast<const float4*>(q)[idx];
    const float* f = reinterpret_cast<const float*>(&v);
    _Float16 h[4];
#pragma unroll
    for (int i = 0; i < 4; ++i) h[i] = (_Float16)f[i];
    reinterpret_cast<uint2*>(qo)[idx] = *reinterpret_cast<uint2*>(h);
    return;
  }
  const float* in;
  _Float16* out;
  int R, C, bx, by;
  bool perm;
  if (blk < 4096 + 3072) {  // Wqkv: grid (96, 32)
    const int lo = blk - 4096;
    bx = lo % 96;
    by = lo / 96;
    in = wqkv; out = wqkvo; R = 1024; C = 3072; perm = true;
  } else {  // Wproj: grid (32, 32)
    const int lo = blk - 7168;
    bx = lo & 31;
    by = lo >> 5;
    in = wproj; out = wprojo; R = 1024; C = 1024; perm = false;
  }
  const int tr = t >> 5, tc = t & 31;
  const int r0 = by * 32, c0 = bx * 32;
#pragma unroll
  for (int rr = 0; rr < 32; rr += 8)
    tile[tr + rr][tc] = in[(size_t)(r0 + tr + rr) * C + c0 + tc];
  __syncthreads();
#pragma unroll
  for (int rr = 0; rr < 32; rr += 8) {
    const int c = c0 + tr + rr;
    int d = c;
    if (perm) {  // columns -> [q(1024) | k(1024) | v(1024)]
      const int h = c / 192, r = c - h * 192;
      d = (r < 64) ? h * 64 + r
                   : (r < 128 ? 1024 + h * 64 + (r - 64) : 2048 + h * 64 + (r - 128));
    }
    out[(size_t)d * R + r0 + tc] = (_Float16)tile[tc][tr + rr];
  }
}

// ---------------- QKV GEMM, 256x256 tile, 8-phase counted-vmcnt schedule -------------
// 512 thr = 8 waves (2M x 4N); wave tile 128x64; acc[8][4]; LDS 128KB
// (2 buf x 2 half x 128x64 f16 per array). Per pair-iter (K-tiles 2i,2i+1):
// 8 phases; phase ph: issue ONE half-tile (phases 0-3: kt=2i+1 -> buf1;
// 4-7: kt=2i+2 -> buf0), quadrant compute (2 m-frags x 4 n x K=64 = 16 MFMA).
// Waits only at phases 0/4: vmcnt(2) (= the 2 just-issued loads; prior K-tile's
// halves then complete; barrier aligns all waves). Loads stay in flight across
// 3 barriers. B-frags read once per K-tile, held in regs. T21 swizzle both sides.
__global__ __launch_bounds__(512, 1) void k_gemm_qkv(const _Float16* __restrict__ A,
                                                     const _Float16* __restrict__ Bt,
                                                     const float* __restrict__ bias,
                                                     _Float16* __restrict__ oq,
                                                     _Float16* __restrict__ ok,
                                                     _Float16* __restrict__ ov) {
  constexpr int K = EMB;
  __shared__ _Float16 As[2][2][128 * 64];
  __shared__ _Float16 Bs[2][2][128 * 64];
  const int t = threadIdx.x;
  const int l = t & 63, w = t >> 6;
  const int lr = l & 15, lg = l >> 4;
  const int wm = w >> 2, wn = w & 3;
  // XCD swizzle (192 blocks, bijective): xcd owns 2 m-panels x 12 n-panels
  const int id = blockIdx.x;
  const int xcd = id & 7, wg = id >> 3;        // wg in [0,24)
  const int m0 = (xcd * 2 + wg / 12) * 256;
  const int n0 = (wg % 12) * 256;

  // staging: thread covers rows sr0, sr0+64 of a 128x64 half-tile; LDS dest
  // linear (= t*16 within half), global source block pre-swizzled (T21).
  const int sr0 = t >> 3, scb = t & 7;
  auto stageA = [&](int buf, int half, int kt) {
    const _Float16* g = A + (size_t)(m0 + half * 128) * K + kt * 64;
    _Float16* d = &As[buf][half][0];
    gload_lds16(g + (size_t)sr0 * K + (scb ^ (sr0 & 7)) * 8, d + sr0 * 64 + scb * 8);
    const int r1 = sr0 + 64;
    gload_lds16(g + (size_t)r1 * K + (scb ^ (r1 & 7)) * 8, d + r1 * 64 + scb * 8);
  };
  auto stageB = [&](int buf, int half, int kt) {
    const _Float16* g = Bt + (size_t)(n0 + half * 128) * K + kt * 64;
    _Float16* d = &Bs[buf][half][0];
    gload_lds16(g + (size_t)sr0 * K + (scb ^ (sr0 & 7)) * 8, d + sr0 * 64 + scb * 8);
    const int r1 = sr0 + 64;
    gload_lds16(g + (size_t)r1 * K + (scb ^ (r1 & 7)) * 8, d + r1 * 64 + scb * 8);
  };

  f32x4 acc[8][4];
#pragma unroll
  for (int m = 0; m < 8; ++m)
#pragma unroll
    for (int n = 0; n < 4; ++n) acc[m][n] = f32x4{0.f, 0.f, 0.f, 0.f};

  // prologue: K-tile 0 into buf0 (4 half-tiles, 8 loads/thread)
  stageA(0, 0, 0);
  stageA(0, 1, 0);
  stageB(0, 0, 0);
  stageB(0, 1, 0);

  const int bhh = wn >> 1, brow0 = (wn & 1) * 64;
  f16x8 bf[4][2];

  for (int pair = 0; pair < 8; ++pair) {
#pragma unroll
    for (int ph = 0; ph < 8; ++ph) {
      const int buf = ph >> 2, q = ph & 3;
      // issue one half-tile (2 loads/thread)
      bool issued = true;
      if (ph < 4) {  // kt = 2*pair+1 -> buf1 (old buf1 reads ended last pair)
        const int kt = 2 * pair + 1;
        if (q == 0) stageA(1, 0, kt);
        else if (q == 1) stageA(1, 1, kt);
        else if (q == 2) stageB(1, 0, kt);
        else stageB(1, 1, kt);
      } else if (pair + 1 < 8) {  // kt = 2*pair+2 -> buf0 (freed at ph3 barrier)
        const int kt = 2 * pair + 2;
        if (q == 0) stageA(0, 0, kt);
        else if (q == 1) stageA(0, 1, kt);
        else if (q == 2) stageB(0, 0, kt);
        else stageB(0, 1, kt);
      } else {
        issued = false;
      }
      if (q == 0) {
        // this K-tile's 4 half-tiles are the oldest outstanding; only the
        // just-issued half-tile (2 loads) may remain in flight
        if (issued)
          asm volatile("s_waitcnt vmcnt(2)" ::: "memory");
        else
          asm volatile("s_waitcnt vmcnt(0)" ::: "memory");
        __builtin_amdgcn_s_barrier();
        // B-frags for this K-tile (held in regs for 4 phases)
#pragma unroll
        for (int nf = 0; nf < 4; ++nf)
#pragma unroll
          for (int ks = 0; ks < 2; ++ks)
            bf[nf][ks] = swzread(&Bs[buf][bhh][0], brow0 + nf * 16 + lr, ks * 4 + lg);
      }
      // A-frags for this quadrant (m-frags 2q, 2q+1)
      f16x8 af[2][2];
#pragma unroll
      for (int dm = 0; dm < 2; ++dm)
#pragma unroll
        for (int ks = 0; ks < 2; ++ks)
          af[dm][ks] = swzread(&As[buf][wm][0], (q * 2 + dm) * 16 + lr, ks * 4 + lg);
      __builtin_amdgcn_s_setprio(1);
#pragma unroll
      for (int dm = 0; dm < 2; ++dm)
#pragma unroll
        for (int nf = 0; nf < 4; ++nf)
#pragma unroll
          for (int ks = 0; ks < 2; ++ks)
            acc[q * 2 + dm][nf] =
                mfma16(af[dm][ks], bf[nf][ks], acc[q * 2 + dm][nf]);
      __builtin_amdgcn_s_setprio(0);
      __builtin_amdgcn_s_barrier();  // phase end: frees this phase's liveness
    }
  }

  // epilogue scatter (sec block-uniform: 256-wide n-tile within 1024 section)
  const int sec = n0 >> 10;  // 0=q 1=k 2=v
#pragma unroll
  for (int mf = 0; mf < 8; ++mf) {
#pragma unroll
    for (int nf = 0; nf < 4; ++nf) {
      const int col = n0 + wn * 64 + nf * 16 + lr;
      const int cc = col & 1023;
      const int h = cc >> 6, r = cc & 63;
      const float bv = bias[h * 192 + sec * 64 + r];
      const int row0 = m0 + wm * 128 + mf * 16 + lg * 4;
      const int b = row0 >> 11, s0 = row0 & (SEQ - 1);
      if (sec == 2) {  // V^T: i -> s consecutive, 4-aligned -> one 8B store
        f16x4 vv;
#pragma unroll
        for (int i = 0; i < 4; ++i) vv[i] = (_Float16)(acc[mf][nf][i] + bv);
        *(f16x4*)&ov[(((size_t)b * NH + h) * HD_ + r) * SEQ + s0] = vv;
      } else {
#pragma unroll
        for (int i = 0; i < 4; ++i) {
          const float v = acc[mf][nf][i] + bv;
          const size_t dst = (((size_t)b * NH + h) * SEQ + s0 + i) * HD_ + r;
          if (sec == 0)
            oq[dst] = (_Float16)(v * 11.5415603f);  // 8*log2(e) folded
          else
            ok[dst] = (_Float16)v;
        }
      }
    }
  }
}

// ---------------- proj GEMM: a_o f16 x Wproj_t f16^T -> f32 + bias ----------------
// XCD swizzle (256 blocks, bijective): xcd owns 4 m-panels x all 8 n (~3MB).
__global__ __launch_bounds__(256) void k_gemm_proj(const _Float16* __restrict__ A,
                                                   const _Float16* __restrict__ Bt,
                                                   const float* __restrict__ bias,
                                                   float* __restrict__ of) {
  constexpr int K = EMB, N = EMB;
  __shared__ _Float16 As[2][128 * 32];
  __shared__ _Float16 Bs[2][128 * 32];
  const int t = threadIdx.x;
  const int l = t & 63, w = t >> 6;
  const int lr = l & 15, lg = l >> 4;
  const int wr = w >> 1, wc = w & 1;
  const int id = blockIdx.x;
  const int xcd = id & 7, wg = id >> 3;       // wg in [0,32)
  const int m0 = (xcd * 4 + wg / 8) * 128;
  const int n0 = (wg & 7) * 128;

  auto stage = [&](int buf, int k0) {
#pragma unroll
    for (int j = 0; j < 2; ++j) {
      const int c = t + 256 * j;
      const int row = c >> 2, cb = c & 3;
      gload_lds16(A + (size_t)(m0 + row) * K + k0 + cb * 8, &As[buf][c * 8]);
      gload_lds16(Bt + (size_t)(n0 + row) * K + k0 + cb * 8, &Bs[buf][c * 8]);
    }
  };

  f32x4 acc[4][4];
#pragma unroll
  for (int m = 0; m < 4; ++m)
#pragma unroll
    for (int n = 0; n < 4; ++n) acc[m][n] = f32x4{0.f, 0.f, 0.f, 0.f};

  stage(0, 0);
  const int NT = K / 32;
  int cur = 0;
  for (int kt = 0; kt < NT; ++kt) {
    __syncthreads();
    if (kt + 1 < NT) stage(cur ^ 1, (kt + 1) * 32);
    f16x8 af[4], bf[4];
#pragma unroll
    for (int m = 0; m < 4; ++m)
      af[m] = *(const f16x8*)&As[cur][(wr * 64 + m * 16 + lr) * 32 + lg * 8];
#pragma unroll
    for (int n = 0; n < 4; ++n)
      bf[n] = *(const f16x8*)&Bs[cur][(wc * 64 + n * 16 + lr) * 32 + lg * 8];
#pragma unroll
    for (int m = 0; m < 4; ++m)
#pragma unroll
      for (int n = 0; n < 4; ++n) acc[m][n] = mfma16(af[m], bf[n], acc[m][n]);
    cur ^= 1;
  }

#pragma unroll
  for (int m = 0; m < 4; ++m)
#pragma unroll
    for (int n = 0; n < 4; ++n)
#pragma unroll
      for (int i = 0; i < 4; ++i) {
        const int row = m0 + wr * 64 + m * 16 + lg * 4 + i;
        const int col = n0 + wc * 64 + n * 16 + lr;
        of[(size_t)row * N + col] = acc[m][n][i] + bias[col];
      }
}

// ---------------- flash attention, single-pass, 3-buf counted-vmcnt pipeline --------
// (R18, proven 79.8us) grid 512 = (bh, 128 q-rows); 512 threads; 64KB LDS.
__global__ __launch_bounds__(512) void k_attn(const _Float16* __restrict__ qs,
                                              const _Float16* __restrict__ ks,
                                              const _Float16* __restrict__ vt,
                                              _Float16* __restrict__ ao) {
  __shared__ _Float16 Kt[3][64][64];   // [buf][kv][d]   swizzled rows (128B)
  __shared__ _Float16 Vt[3][64][64];   // [buf][d][kv]   swizzled rows
  __shared__ _Float16 Pl[8][16][64];   // per-wave P [q][kv], swizzled rows
  const int t = threadIdx.x;
  const int l = t & 63, w = t >> 6;          // w in [0,8)
  const int lr = l & 15, lg = l >> 4;
  // XCD-grouping: id&7 -> XCD; per XCD: 4 heads x 16 q-blocks
  const int id = blockIdx.x;
  const int xc = id & 7, m_ = id >> 3;       // m_ in [0,64)
  const int bh = xc + 8 * (m_ >> 4);         // 4 heads per XCD
  const int qb = (m_ & 15) * 128 + w * 16;   // 128 q-rows per block

  // Q fragments (B-operand: n=q=lr, k=d)
  const size_t qoff = ((size_t)bh * SEQ + qb + lr) * HD_;
  const f16x8 qf0 = *(const f16x8*)(qs + qoff + lg * 8);
  const f16x8 qf1 = *(const f16x8*)(qs + qoff + 32 + lg * 8);

  const _Float16* kbase = ks + (size_t)bh * SEQ * HD_;
  const _Float16* vbase = vt + (size_t)bh * HD_ * SEQ;

  // async staging: 512 threads cover the 64x64 tile in one pass each for K,V.
  // LDS dest linear (DMA rule); global SOURCE block pre-swizzled (T21).
  const int srow = t >> 3, scb = t & 7;      // srow in [0,64)
  auto stage = [&](const int buf, const int kv0) {
    gload_lds16(kbase + (size_t)(kv0 + srow) * HD_ + (scb ^ (srow & 7)) * 8,
                &Kt[buf][srow][scb * 8]);
    gload_lds16(vbase + (size_t)srow * SEQ + kv0 + (scb ^ (srow & 7)) * 8,
                &Vt[buf][srow][scb * 8]);
  };

  stage(0, 0);
  stage(1, 64);

  float mr = -1e30f, lsum = 0.f;
  f32x4 oacc[4];
#pragma unroll
  for (int n = 0; n < 4; ++n) oacc[n] = f32x4{0.f, 0.f, 0.f, 0.f};

  const int NT = SEQ / 64;  // 32 tiles
  int cur = 0;              // it % 3
  for (int it = 0; it < NT; ++it) {
    // wait own tile-it DMAs (2 newest may stay in flight), align all waves
    if (it == NT - 1)
      asm volatile("s_waitcnt vmcnt(0)" ::: "memory");
    else
      asm volatile("s_waitcnt vmcnt(2)" ::: "memory");
    __builtin_amdgcn_s_barrier();
    // issue tile it+2 into the buffer read in iter it-1 (barrier-protected)
    if (it + 2 < NT) {
      int nb = cur + 2;
      if (nb >= 3) nb -= 3;
      stage(nb, (it + 2) * 64);
    }

    // S^T = K Q^T : lane holds S[kv=16*t4+4*lg+i][q=lr]   (base-2 logits)
    f32x4 sa[4];
    __builtin_amdgcn_s_setprio(1);
#pragma unroll
    for (int t4 = 0; t4 < 4; ++t4) {
      const int r = t4 * 16 + lr;
      const f16x8 kf0 = swzread(&Kt[cur][0][0], r, lg);
      const f16x8 kf1 = swzread(&Kt[cur][0][0], r, lg + 4);
      f32x4 s = mfma16(kf0, qf0, f32x4{0.f, 0.f, 0.f, 0.f});
      sa[t4] = mfma16(kf1, qf1, s);
    }
    __builtin_amdgcn_s_setprio(0);

    // online softmax (per-lane q-row), defer-max with THR=8 (base-2)
    float t01 = fmaxf(fmaxf(sa[0][0], sa[0][1]), fmaxf(sa[0][2], sa[0][3]));
    float t23 = fmaxf(fmaxf(sa[1][0], sa[1][1]), fmaxf(sa[1][2], sa[1][3]));
    float t45 = fmaxf(fmaxf(sa[2][0], sa[2][1]), fmaxf(sa[2][2], sa[2][3]));
    float t67 = fmaxf(fmaxf(sa[3][0], sa[3][1]), fmaxf(sa[3][2], sa[3][3]));
    float tm = fmaxf(fmaxf(t01, t23), fmaxf(t45, t67));
    tm = fmaxf(tm, __shfl_xor(tm, 16));
    tm = fmaxf(tm, __shfl_xor(tm, 32));

    // negligible-tile skip: whole tile < 2^-24 relative to running max
    if (__all(tm < mr - 24.0f)) {
      cur = (cur + 1 == 3) ? 0 : cur + 1;
      continue;
    }

    if (__any(tm > mr + 8.0f)) {  // wave-uniform rescale
      const float nm = fmaxf(mr, tm);
      const float corr = exp2f(mr - nm);
      mr = nm;
      lsum *= corr;
      float cb4[4];
#pragma unroll
      for (int i = 0; i < 4; ++i)
        cb4[i] = __shfl(corr, (l & 48) + ((l >> 4) << 2) + i);
#pragma unroll
      for (int n = 0; n < 4; ++n)
#pragma unroll
        for (int i = 0; i < 4; ++i) oacc[n][i] *= cb4[i];
    }

    float ts = 0.f;
    char* plbase = (char*)&Pl[w][0][0];
#pragma unroll
    for (int t4 = 0; t4 < 4; ++t4) {
      f16x4 pp;
#pragma unroll
      for (int i = 0; i < 4; ++i) {
        const float p = exp2f(sa[t4][i] - mr);
        ts += p;
        pp[i] = (_Float16)p;
      }
      // P[q=lr][kv=t4*16+lg*4+i], swizzled row (XOR bits 4-6, 8B aligned)
      *(f16x4*)(plbase + lr * 128 + ((t4 * 32 + lg * 8) ^ ((lr & 7) << 4))) = pp;
    }
    ts += __shfl_xor(ts, 16);
    ts += __shfl_xor(ts, 32);
    lsum += ts;

    // O += P V (A=P[q][kv], B=V^T[d][kv])
    const f16x8 aP0 = swzread(&Pl[w][0][0], lr, lg);
    const f16x8 aP1 = swzread(&Pl[w][0][0], lr, lg + 4);
    __builtin_amdgcn_s_setprio(1);
#pragma unroll
    for (int n = 0; n < 4; ++n) {
      const int d = n * 16 + lr;
      const f16x8 bv0 = swzread(&Vt[cur][0][0], d, lg);
      const f16x8 bv1 = swzread(&Vt[cur][0][0], d, lg + 4);
      oacc[n] = mfma16(aP0, bv0, oacc[n]);
      oacc[n] = mfma16(aP1, bv1, oacc[n]);
    }
    __builtin_amdgcn_s_setprio(0);

    cur = (cur + 1 == 3) ? 0 : cur + 1;
  }

  // epilogue: fetch lsum for q=4*lg+i, normalize, store f16 to a_o
  float ls4[4];
#pragma unroll
  for (int i = 0; i < 4; ++i)
    ls4[i] = __shfl(lsum, (l & 48) + ((l >> 4) << 2) + i);
  const int b = bh >> 4, h = bh & 15;
#pragma unroll
  for (int n = 0; n < 4; ++n)
#pragma unroll
    for (int i = 0; i < 4; ++i) {
      const int row = qb + ((l >> 4) << 2) + i;
      ao[((size_t)b * SEQ + row) * EMB + h * HD_ + n * 16 + lr] =
          (_Float16)(oacc[n][i] / ls4[i]);
    }
}

extern "C" void kernel_launch(void* const* d_in, const int* in_sizes, int n_in,
                              void* d_out, int out_size, void* d_ws, size_t ws_size,
                              hipStream_t stream) {
  const float* query = (const float*)d_in[0];
  const float* Wqkv = (const float*)d_in[3];
  const float* bqkv = (const float*)d_in[4];
  const float* Wproj = (const float*)d_in[5];
  const float* bproj = (const float*)d_in[6];
  float* out = (float*)d_out;

  char* ws = (char*)d_ws;
  const size_t MB = 1024 * 1024;
  _Float16* q_f16   = (_Float16*)(ws + 0);         // 8MB; dead after QKV GEMM
  _Float16* Wqkv_t  = (_Float16*)(ws + 16 * MB);   // 6MB f16 (rows: q|k|v)
  _Float16* q_s     = (_Float16*)(ws + 24 * MB);   // 8MB [32][2048][64]
  _Float16* k_s     = (_Float16*)(ws + 32 * MB);   // 8MB
  _Float16* v_t     = (_Float16*)(ws + 40 * MB);   // 8MB [32][64][2048]
  _Float16* Wproj_t = (_Float16*)(ws + 48 * MB);   // 2MB
  _Float16* a_o     = (_Float16*)(ws + 51 * MB);   // 8MB

  const int M = BATCH * SEQ;  // 4096
  k_prep<<<dim3(8192), 256, 0, stream>>>(query, q_f16, Wqkv, Wqkv_t, Wproj, Wproj_t);
  k_gemm_qkv<<<dim3(192), 512, 0, stream>>>(q_f16, Wqkv_t, bqkv, q_s, k_s, v_t);
  k_attn<<<dim3(512), 512, 0, stream>>>(q_s, k_s, v_t, a_o);
  k_gemm_proj<<<dim3(256), 256, 0, stream>>>(a_o, Wproj_t, bproj, out);
}

// Round 20
// 143.677 us; speedup vs baseline: 1.0887x; 1.0102x over previous
//
#include <hip/hip_runtime.h>
#include <hip/hip_bf16.h>
#include <stdint.h>

typedef __attribute__((ext_vector_type(8))) _Float16 f16x8;
typedef __attribute__((ext_vector_type(4))) _Float16 f16x4;
typedef __attribute__((ext_vector_type(4))) float f32x4;

static constexpr int BATCH = 2;
static constexpr int SEQ = 2048;
static constexpr int EMB = 1024;
static constexpr int NH = 16;
static constexpr int HD_ = 64;

#define AS1 __attribute__((address_space(1)))
#define AS3 __attribute__((address_space(3)))

__device__ __forceinline__ void gload_lds16(const void* g, void* l) {
  __builtin_amdgcn_global_load_lds((const AS1 uint32_t*)g, (AS3 uint32_t*)l, 16, 0, 0);
}

__device__ __forceinline__ f32x4 mfma16(f16x8 a, f16x8 b, f32x4 c) {
  return __builtin_amdgcn_mfma_f32_16x16x32_f16(a, b, c, 0, 0, 0);
}

// swizzled 16B-block read from a 128B-row LDS tile: byte ^= (row&7)<<4
__device__ __forceinline__ f16x8 swzread(const _Float16* base, int row, int blk) {
  return *(const f16x8*)((const char*)base + row * 128 +
                         ((blk * 16) ^ ((row & 7) << 4)));
}

// ---------------- merged prep: convert q -> f16, transpose Wqkv (perm), Wproj --------
// blocks [0,4096): q convert; [4096,7168): Wqkv transpose+perm; [7168,8192): Wproj.
__global__ __launch_bounds__(256) void k_prep(const float* __restrict__ q,
                                              _Float16* __restrict__ qo,
                                              const float* __restrict__ wqkv,
                                              _Float16* __restrict__ wqkvo,
                                              const float* __restrict__ wproj,
                                              _Float16* __restrict__ wprojo) {
  __shared__ float tile[32][33];
  const int blk = blockIdx.x;
  const int t = threadIdx.x;
  if (blk < 4096) {  // convert: 4096*256 float4 = 4096*1024 floats
    const int idx = blk * 256 + t;
    float4 v = reinterpret_cast<const float4*>(q)[idx];
    const float* f = reinterpret_cast<const float*>(&v);
    _Float16 h[4];
#pragma unroll
    for (int i = 0; i < 4; ++i) h[i] = (_Float16)f[i];
    reinterpret_cast<uint2*>(qo)[idx] = *reinterpret_cast<uint2*>(h);
    return;
  }
  const float* in;
  _Float16* out;
  int R, C, bx, by;
  bool perm;
  if (blk < 4096 + 3072) {  // Wqkv: grid (96, 32)
    const int lo = blk - 4096;
    bx = lo % 96;
    by = lo / 96;
    in = wqkv; out = wqkvo; R = 1024; C = 3072; perm = true;
  } else {  // Wproj: grid (32, 32)
    const int lo = blk - 7168;
    bx = lo & 31;
    by = lo >> 5;
    in = wproj; out = wprojo; R = 1024; C = 1024; perm = false;
  }
  const int tr = t >> 5, tc = t & 31;
  const int r0 = by * 32, c0 = bx * 32;
#pragma unroll
  for (int rr = 0; rr < 32; rr += 8)
    tile[tr + rr][tc] = in[(size_t)(r0 + tr + rr) * C + c0 + tc];
  __syncthreads();
#pragma unroll
  for (int rr = 0; rr < 32; rr += 8) {
    const int c = c0 + tr + rr;
    int d = c;
    if (perm) {  // columns -> [q(1024) | k(1024) | v(1024)]
      const int h = c / 192, r = c - h * 192;
      d = (r < 64) ? h * 64 + r
                   : (r < 128 ? 1024 + h * 64 + (r - 64) : 2048 + h * 64 + (r - 128));
    }
    out[(size_t)d * R + r0 + tc] = (_Float16)tile[tc][tr + rr];
  }
}

// ---------------- QKV GEMM, 256x256 tile, 8-phase counted-vmcnt schedule -------------
// (R19, proven) 512 thr = 8 waves (2M x 4N); wave tile 128x64; LDS 128KB.
__global__ __launch_bounds__(512, 1) void k_gemm_qkv(const _Float16* __restrict__ A,
                                                     const _Float16* __restrict__ Bt,
                                                     const float* __restrict__ bias,
                                                     _Float16* __restrict__ oq,
                                                     _Float16* __restrict__ ok,
                                                     _Float16* __restrict__ ov) {
  constexpr int K = EMB;
  __shared__ _Float16 As[2][2][128 * 64];
  __shared__ _Float16 Bs[2][2][128 * 64];
  const int t = threadIdx.x;
  const int l = t & 63, w = t >> 6;
  const int lr = l & 15, lg = l >> 4;
  const int wm = w >> 2, wn = w & 3;
  // XCD swizzle (192 blocks, bijective): xcd owns 2 m-panels x 12 n-panels
  const int id = blockIdx.x;
  const int xcd = id & 7, wg = id >> 3;        // wg in [0,24)
  const int m0 = (xcd * 2 + wg / 12) * 256;
  const int n0 = (wg % 12) * 256;

  const int sr0 = t >> 3, scb = t & 7;
  auto stageA = [&](int buf, int half, int kt) {
    const _Float16* g = A + (size_t)(m0 + half * 128) * K + kt * 64;
    _Float16* d = &As[buf][half][0];
    gload_lds16(g + (size_t)sr0 * K + (scb ^ (sr0 & 7)) * 8, d + sr0 * 64 + scb * 8);
    const int r1 = sr0 + 64;
    gload_lds16(g + (size_t)r1 * K + (scb ^ (r1 & 7)) * 8, d + r1 * 64 + scb * 8);
  };
  auto stageB = [&](int buf, int half, int kt) {
    const _Float16* g = Bt + (size_t)(n0 + half * 128) * K + kt * 64;
    _Float16* d = &Bs[buf][half][0];
    gload_lds16(g + (size_t)sr0 * K + (scb ^ (sr0 & 7)) * 8, d + sr0 * 64 + scb * 8);
    const int r1 = sr0 + 64;
    gload_lds16(g + (size_t)r1 * K + (scb ^ (r1 & 7)) * 8, d + r1 * 64 + scb * 8);
  };

  f32x4 acc[8][4];
#pragma unroll
  for (int m = 0; m < 8; ++m)
#pragma unroll
    for (int n = 0; n < 4; ++n) acc[m][n] = f32x4{0.f, 0.f, 0.f, 0.f};

  stageA(0, 0, 0);
  stageA(0, 1, 0);
  stageB(0, 0, 0);
  stageB(0, 1, 0);

  const int bhh = wn >> 1, brow0 = (wn & 1) * 64;
  f16x8 bf[4][2];

  for (int pair = 0; pair < 8; ++pair) {
#pragma unroll
    for (int ph = 0; ph < 8; ++ph) {
      const int buf = ph >> 2, q = ph & 3;
      bool issued = true;
      if (ph < 4) {
        const int kt = 2 * pair + 1;
        if (q == 0) stageA(1, 0, kt);
        else if (q == 1) stageA(1, 1, kt);
        else if (q == 2) stageB(1, 0, kt);
        else stageB(1, 1, kt);
      } else if (pair + 1 < 8) {
        const int kt = 2 * pair + 2;
        if (q == 0) stageA(0, 0, kt);
        else if (q == 1) stageA(0, 1, kt);
        else if (q == 2) stageB(0, 0, kt);
        else stageB(0, 1, kt);
      } else {
        issued = false;
      }
      if (q == 0) {
        if (issued)
          asm volatile("s_waitcnt vmcnt(2)" ::: "memory");
        else
          asm volatile("s_waitcnt vmcnt(0)" ::: "memory");
        __builtin_amdgcn_s_barrier();
#pragma unroll
        for (int nf = 0; nf < 4; ++nf)
#pragma unroll
          for (int ks = 0; ks < 2; ++ks)
            bf[nf][ks] = swzread(&Bs[buf][bhh][0], brow0 + nf * 16 + lr, ks * 4 + lg);
      }
      f16x8 af[2][2];
#pragma unroll
      for (int dm = 0; dm < 2; ++dm)
#pragma unroll
        for (int ks = 0; ks < 2; ++ks)
          af[dm][ks] = swzread(&As[buf][wm][0], (q * 2 + dm) * 16 + lr, ks * 4 + lg);
      __builtin_amdgcn_s_setprio(1);
#pragma unroll
      for (int dm = 0; dm < 2; ++dm)
#pragma unroll
        for (int nf = 0; nf < 4; ++nf)
#pragma unroll
          for (int ks = 0; ks < 2; ++ks)
            acc[q * 2 + dm][nf] =
                mfma16(af[dm][ks], bf[nf][ks], acc[q * 2 + dm][nf]);
      __builtin_amdgcn_s_setprio(0);
      __builtin_amdgcn_s_barrier();
    }
  }

  const int sec = n0 >> 10;  // 0=q 1=k 2=v
#pragma unroll
  for (int mf = 0; mf < 8; ++mf) {
#pragma unroll
    for (int nf = 0; nf < 4; ++nf) {
      const int col = n0 + wn * 64 + nf * 16 + lr;
      const int cc = col & 1023;
      const int h = cc >> 6, r = cc & 63;
      const float bv = bias[h * 192 + sec * 64 + r];
      const int row0 = m0 + wm * 128 + mf * 16 + lg * 4;
      const int b = row0 >> 11, s0 = row0 & (SEQ - 1);
      if (sec == 2) {  // V^T: i -> s consecutive, 4-aligned -> one 8B store
        f16x4 vv;
#pragma unroll
        for (int i = 0; i < 4; ++i) vv[i] = (_Float16)(acc[mf][nf][i] + bv);
        *(f16x4*)&ov[(((size_t)b * NH + h) * HD_ + r) * SEQ + s0] = vv;
      } else {
#pragma unroll
        for (int i = 0; i < 4; ++i) {
          const float v = acc[mf][nf][i] + bv;
          const size_t dst = (((size_t)b * NH + h) * SEQ + s0 + i) * HD_ + r;
          if (sec == 0)
            oq[dst] = (_Float16)(v * 11.5415603f);  // 8*log2(e) folded
          else
            ok[dst] = (_Float16)v;
        }
      }
    }
  }
}

// ---------------- proj GEMM: a_o f16 x Wproj_t f16^T -> f32 + bias ----------------
// XCD swizzle (256 blocks, bijective): xcd owns 4 m-panels x all 8 n (~3MB).
__global__ __launch_bounds__(256) void k_gemm_proj(const _Float16* __restrict__ A,
                                                   const _Float16* __restrict__ Bt,
                                                   const float* __restrict__ bias,
                                                   float* __restrict__ of) {
  constexpr int K = EMB, N = EMB;
  __shared__ _Float16 As[2][128 * 32];
  __shared__ _Float16 Bs[2][128 * 32];
  const int t = threadIdx.x;
  const int l = t & 63, w = t >> 6;
  const int lr = l & 15, lg = l >> 4;
  const int wr = w >> 1, wc = w & 1;
  const int id = blockIdx.x;
  const int xcd = id & 7, wg = id >> 3;       // wg in [0,32)
  const int m0 = (xcd * 4 + wg / 8) * 128;
  const int n0 = (wg & 7) * 128;

  auto stage = [&](int buf, int k0) {
#pragma unroll
    for (int j = 0; j < 2; ++j) {
      const int c = t + 256 * j;
      const int row = c >> 2, cb = c & 3;
      gload_lds16(A + (size_t)(m0 + row) * K + k0 + cb * 8, &As[buf][c * 8]);
      gload_lds16(Bt + (size_t)(n0 + row) * K + k0 + cb * 8, &Bs[buf][c * 8]);
    }
  };

  f32x4 acc[4][4];
#pragma unroll
  for (int m = 0; m < 4; ++m)
#pragma unroll
    for (int n = 0; n < 4; ++n) acc[m][n] = f32x4{0.f, 0.f, 0.f, 0.f};

  stage(0, 0);
  const int NT = K / 32;
  int cur = 0;
  for (int kt = 0; kt < NT; ++kt) {
    __syncthreads();
    if (kt + 1 < NT) stage(cur ^ 1, (kt + 1) * 32);
    f16x8 af[4], bf[4];
#pragma unroll
    for (int m = 0; m < 4; ++m)
      af[m] = *(const f16x8*)&As[cur][(wr * 64 + m * 16 + lr) * 32 + lg * 8];
#pragma unroll
    for (int n = 0; n < 4; ++n)
      bf[n] = *(const f16x8*)&Bs[cur][(wc * 64 + n * 16 + lr) * 32 + lg * 8];
#pragma unroll
    for (int m = 0; m < 4; ++m)
#pragma unroll
      for (int n = 0; n < 4; ++n) acc[m][n] = mfma16(af[m], bf[n], acc[m][n]);
    cur ^= 1;
  }

#pragma unroll
  for (int m = 0; m < 4; ++m)
#pragma unroll
    for (int n = 0; n < 4; ++n)
#pragma unroll
      for (int i = 0; i < 4; ++i) {
        const int row = m0 + wr * 64 + m * 16 + lg * 4 + i;
        const int col = n0 + wc * 64 + n * 16 + lr;
        of[(size_t)row * N + col] = acc[m][n][i] + bias[col];
      }
}

// ---------------- flash attention, single-pass, KVBLK=128 (2 sub-tiles / barrier) ----
// grid 512 = (bh, 128 q-rows); 512 threads; 80KB LDS = exactly 2 blocks/CU.
// Per iter: one __syncthreads + one 128-kv stage (4 DMAs/thread), then two
// 64-kv sub-tile passes (QK -> softmax -> P -> PV) back-to-back. Halves the
// barrier-event count (32 -> 16) and doubles the DMA latency-hiding window.
// V stored as 2x[64][64] sub-tiles so the 128B-row T21 swizzle is unchanged.
// P buffer reused across sub-tiles (same-wave LDS ops are in-order).
__global__ __launch_bounds__(512) void k_attn(const _Float16* __restrict__ qs,
                                              const _Float16* __restrict__ ks,
                                              const _Float16* __restrict__ vt,
                                              _Float16* __restrict__ ao) {
  __shared__ _Float16 Kt[2][128][64];     // [buf][kv][d]  swizzled rows (128B)
  __shared__ _Float16 Vt[2][2][64][64];   // [buf][sub][d][kv'] swizzled rows
  __shared__ _Float16 Pl[8][16][64];      // per-wave P [q][kv'], swizzled rows
  const int t = threadIdx.x;
  const int l = t & 63, w = t >> 6;          // w in [0,8)
  const int lr = l & 15, lg = l >> 4;
  // XCD-grouping: id&7 -> XCD; per XCD: 4 heads x 16 q-blocks
  const int id = blockIdx.x;
  const int xc = id & 7, m_ = id >> 3;       // m_ in [0,64)
  const int bh = xc + 8 * (m_ >> 4);         // 4 heads per XCD
  const int qb = (m_ & 15) * 128 + w * 16;   // 128 q-rows per block

  // Q fragments (B-operand: n=q=lr, k=d)
  const size_t qoff = ((size_t)bh * SEQ + qb + lr) * HD_;
  const f16x8 qf0 = *(const f16x8*)(qs + qoff + lg * 8);
  const f16x8 qf1 = *(const f16x8*)(qs + qoff + 32 + lg * 8);

  const _Float16* kbase = ks + (size_t)bh * SEQ * HD_;
  const _Float16* vbase = vt + (size_t)bh * HD_ * SEQ;

  // staging: thread covers K rows {srow, srow+64} and V sub-tiles 0,1 row srow.
  // LDS dest linear (DMA rule); global SOURCE block pre-swizzled (T21;
  // (srow+64)&7 == srow&7 so the involution matches the read side).
  const int srow = t >> 3, scb = t & 7;      // srow in [0,64)
  auto stage = [&](const int buf, const int kv0) {
    gload_lds16(kbase + (size_t)(kv0 + srow) * HD_ + (scb ^ (srow & 7)) * 8,
                &Kt[buf][srow][scb * 8]);
    const int r1 = srow + 64;
    gload_lds16(kbase + (size_t)(kv0 + r1) * HD_ + (scb ^ (srow & 7)) * 8,
                &Kt[buf][r1][scb * 8]);
    gload_lds16(vbase + (size_t)srow * SEQ + kv0 + (scb ^ (srow & 7)) * 8,
                &Vt[buf][0][srow][scb * 8]);
    gload_lds16(vbase + (size_t)srow * SEQ + kv0 + 64 + (scb ^ (srow & 7)) * 8,
                &Vt[buf][1][srow][scb * 8]);
  };

  stage(0, 0);

  float mr = -1e30f, lsum = 0.f;
  f32x4 oacc[4];
#pragma unroll
  for (int n = 0; n < 4; ++n) oacc[n] = f32x4{0.f, 0.f, 0.f, 0.f};

  char* plbase = (char*)&Pl[w][0][0];
  const int NT = SEQ / 128;  // 16 iters, 2 sub-tiles each
  for (int it = 0; it < NT; ++it) {
    const int cur = it & 1;
    __syncthreads();  // drains vmcnt: buf[cur] DMA complete; prev reads done
    if (it + 1 < NT) stage(cur ^ 1, (it + 1) * 128);

#pragma unroll
    for (int sub = 0; sub < 2; ++sub) {
      // S^T = K Q^T : lane holds S[kv'=16*t4+4*lg+i][q=lr]   (base-2 logits)
      f32x4 sa[4];
      __builtin_amdgcn_s_setprio(1);
#pragma unroll
      for (int t4 = 0; t4 < 4; ++t4) {
        const int r = sub * 64 + t4 * 16 + lr;
        const f16x8 kf0 = swzread(&Kt[cur][0][0], r, lg);
        const f16x8 kf1 = swzread(&Kt[cur][0][0], r, lg + 4);
        f32x4 s = mfma16(kf0, qf0, f32x4{0.f, 0.f, 0.f, 0.f});
        sa[t4] = mfma16(kf1, qf1, s);
      }
      __builtin_amdgcn_s_setprio(0);

      // online softmax (per-lane q-row), defer-max with THR=8 (base-2)
      float t01 = fmaxf(fmaxf(sa[0][0], sa[0][1]), fmaxf(sa[0][2], sa[0][3]));
      float t23 = fmaxf(fmaxf(sa[1][0], sa[1][1]), fmaxf(sa[1][2], sa[1][3]));
      float t45 = fmaxf(fmaxf(sa[2][0], sa[2][1]), fmaxf(sa[2][2], sa[2][3]));
      float t67 = fmaxf(fmaxf(sa[3][0], sa[3][1]), fmaxf(sa[3][2], sa[3][3]));
      float tm = fmaxf(fmaxf(t01, t23), fmaxf(t45, t67));
      tm = fmaxf(tm, __shfl_xor(tm, 16));
      tm = fmaxf(tm, __shfl_xor(tm, 32));

      // negligible sub-tile: contributes < 2^-24 relative to running max
      if (__all(tm < mr - 24.0f)) continue;

      if (__any(tm > mr + 8.0f)) {  // wave-uniform rescale
        const float nm = fmaxf(mr, tm);
        const float corr = exp2f(mr - nm);
        mr = nm;
        lsum *= corr;
        float cb4[4];
#pragma unroll
        for (int i = 0; i < 4; ++i)
          cb4[i] = __shfl(corr, (l & 48) + ((l >> 4) << 2) + i);
#pragma unroll
        for (int n = 0; n < 4; ++n)
#pragma unroll
          for (int i = 0; i < 4; ++i) oacc[n][i] *= cb4[i];
      }

      float ts = 0.f;
#pragma unroll
      for (int t4 = 0; t4 < 4; ++t4) {
        f16x4 pp;
#pragma unroll
        for (int i = 0; i < 4; ++i) {
          const float p = exp2f(sa[t4][i] - mr);
          ts += p;
          pp[i] = (_Float16)p;
        }
        // P[q=lr][kv'=t4*16+lg*4+i], swizzled row (XOR bits 4-6, 8B aligned)
        *(f16x4*)(plbase + lr * 128 + ((t4 * 32 + lg * 8) ^ ((lr & 7) << 4))) = pp;
      }
      ts += __shfl_xor(ts, 16);
      ts += __shfl_xor(ts, 32);
      lsum += ts;

      // O += P V (A=P[q][kv'], B=V^T sub-tile [d][kv'])
      const f16x8 aP0 = swzread(&Pl[w][0][0], lr, lg);
      const f16x8 aP1 = swzread(&Pl[w][0][0], lr, lg + 4);
      __builtin_amdgcn_s_setprio(1);
#pragma unroll
      for (int n = 0; n < 4; ++n) {
        const int d = n * 16 + lr;
        const f16x8 bv0 = swzread(&Vt[cur][sub][0][0], d, lg);
        const f16x8 bv1 = swzread(&Vt[cur][sub][0][0], d, lg + 4);
        oacc[n] = mfma16(aP0, bv0, oacc[n]);
        oacc[n] = mfma16(aP1, bv1, oacc[n]);
      }
      __builtin_amdgcn_s_setprio(0);
    }
  }

  // epilogue: fetch lsum for q=4*lg+i, normalize, store f16 to a_o
  float ls4[4];
#pragma unroll
  for (int i = 0; i < 4; ++i)
    ls4[i] = __shfl(lsum, (l & 48) + ((l >> 4) << 2) + i);
  const int b = bh >> 4, h = bh & 15;
#pragma unroll
  for (int n = 0; n < 4; ++n)
#pragma unroll
    for (int i = 0; i < 4; ++i) {
      const int row = qb + ((l >> 4) << 2) + i;
      ao[((size_t)b * SEQ + row) * EMB + h * HD_ + n * 16 + lr] =
          (_Float16)(oacc[n][i] / ls4[i]);
    }
}

extern "C" void kernel_launch(void* const* d_in, const int* in_sizes, int n_in,
                              void* d_out, int out_size, void* d_ws, size_t ws_size,
                              hipStream_t stream) {
  const float* query = (const float*)d_in[0];
  const float* Wqkv = (const float*)d_in[3];
  const float* bqkv = (const float*)d_in[4];
  const float* Wproj = (const float*)d_in[5];
  const float* bproj = (const float*)d_in[6];
  float* out = (float*)d_out;

  char* ws = (char*)d_ws;
  const size_t MB = 1024 * 1024;
  _Float16* q_f16   = (_Float16*)(ws + 0);         // 8MB; dead after QKV GEMM
  _Float16* Wqkv_t  = (_Float16*)(ws + 16 * MB);   // 6MB f16 (rows: q|k|v)
  _Float16* q_s     = (_Float16*)(ws + 24 * MB);   // 8MB [32][2048][64]
  _Float16* k_s     = (_Float16*)(ws + 32 * MB);   // 8MB
  _Float16* v_t     = (_Float16*)(ws + 40 * MB);   // 8MB [32][64][2048]
  _Float16* Wproj_t = (_Float16*)(ws + 48 * MB);   // 2MB
  _Float16* a_o     = (_Float16*)(ws + 51 * MB);   // 8MB

  const int M = BATCH * SEQ;  // 4096
  k_prep<<<dim3(8192), 256, 0, stream>>>(query, q_f16, Wqkv, Wqkv_t, Wproj, Wproj_t);
  k_gemm_qkv<<<dim3(192), 512, 0, stream>>>(q_f16, Wqkv_t, bqkv, q_s, k_s, v_t);
  k_attn<<<dim3(512), 512, 0, stream>>>(q_s, k_s, v_t, a_o);
  k_gemm_proj<<<dim3(256), 256, 0, stream>>>(a_o, Wproj_t, bproj, out);
}